// Round 6
// baseline (293.501 us; speedup 1.0000x reference)
//
#include <hip/hip_runtime.h>

typedef unsigned short u16;
typedef unsigned int   u32;

typedef short    short8 __attribute__((ext_vector_type(8)));
typedef __bf16   bf16x8 __attribute__((ext_vector_type(8)));
typedef _Float16 half8  __attribute__((ext_vector_type(8)));
typedef float    f32x4  __attribute__((ext_vector_type(4)));

#define S_LEN   2048
#define DM      1024
#define NHEAD   16
#define DK      64
#define KDIM    1024

// ---------- helpers ----------
__device__ __forceinline__ u16 f2bf(float f) {
    u32 u = __builtin_bit_cast(u32, f);
    u += 0x7FFFu + ((u >> 16) & 1u);      // RNE
    return (u16)(u >> 16);
}
__device__ __forceinline__ f32x4 mfma_bf16(short8 a, short8 b, f32x4 c) {
    return __builtin_amdgcn_mfma_f32_16x16x32_bf16(
        __builtin_bit_cast(bf16x8, a), __builtin_bit_cast(bf16x8, b), c, 0, 0, 0);
}
__device__ __forceinline__ f32x4 mfma_f16(half8 a, half8 b, f32x4 c) {
    return __builtin_amdgcn_mfma_f32_16x16x32_f16(a, b, c, 0, 0, 0);
}
__device__ __forceinline__ u32 pk_f16(float a, float b) {
    return __builtin_bit_cast(u32, __builtin_amdgcn_cvt_pkrtz(a, b));
}
__device__ __forceinline__ void gl_lds16(const void* g, void* l) {
    __builtin_amdgcn_global_load_lds(
        (const __attribute__((address_space(1))) u32*)g,
        (__attribute__((address_space(3))) u32*)l, 16, 0, 0);
}
// raw barrier / waitcnt: no compiler-inserted vmcnt(0) drain (prefetch stays in flight)
__device__ __forceinline__ void bar_raw() { asm volatile("s_barrier" ::: "memory"); }
__device__ __forceinline__ void wait_vm4() { asm volatile("s_waitcnt vmcnt(4)" ::: "memory"); }
__device__ __forceinline__ void wait_vm0() { asm volatile("s_waitcnt vmcnt(0)" ::: "memory"); }

// K-row permutation for flash: LDS row rc holds global k-row perm_inv(rc) so that
// PV A-frags are in-lane after S^T: k'(nt,quad,r)=32*(nt>>1)+8*quad+4*(nt&1)+r
__device__ __forceinline__ int perm_inv(int rc) {
    const int nt = rc >> 4, mid = (rc >> 2) & 3, r = rc & 3;
    return 32 * (nt >> 1) + 8 * mid + 4 * (nt & 1) + r;
}

// ---------- fused fp32->bf16 convert + RoPE table build ----------
__global__ void cvt_all(const float4* __restrict__ x,  const float4* __restrict__ Wq,
                        const float4* __restrict__ Wk, const float4* __restrict__ Wv,
                        const float4* __restrict__ Wo,
                        uint2* __restrict__ oX, uint2* __restrict__ oWcat,
                        uint2* __restrict__ oWo,
                        float* __restrict__ sT, float* __restrict__ cT) {
    const int i = blockIdx.x * 256 + threadIdx.x;
    if (i < 3145728) {
        const float4* in;
        uint2* out;
        if (i < 2097152) {
            in = x + i;  out = oX + i;
        } else {
            const int j = i - 2097152;
            const int w = j >> 18, k = j & 262143;
            in  = (w == 0 ? Wq : w == 1 ? Wk : w == 2 ? Wv : Wo) + k;
            out = (w < 3) ? (oWcat + w * 262144 + k) : (oWo + k);
        }
        float4 f = *in;
        uint2 o;
        o.x = (u32)f2bf(f.x) | ((u32)f2bf(f.y) << 16);
        o.y = (u32)f2bf(f.z) | ((u32)f2bf(f.w) << 16);
        *out = o;
    } else {
        const int idx = i - 3145728;            // [0, 65536): i=idx>>11, s=idx&2047
        const float fi = expf(-(float)(idx >> 11) * 0.287823136624255f);
        const float ang = (float)(idx & 2047) * fi;
        sT[idx] = sinf(ang);
        cT[idx] = cosf(ang);
    }
}

// ---------- 256x256 / 8-wave QKV GEMM (R5 redesign) ----------
// Theory: R2's 128x128/4-wave is LDS-port limited (48KB/K-tile for 1.05 MFLOP,
// 21.8 FLOP/LDS-B -> ~90us floor at measured port rates). This kernel doubles
// intensity: BM=BN=256, 8 waves (2M x 4N), wave tile 128x64 (acc[8][4]),
// 42.7 FLOP/LDS-B; ILP-based schedule replaces the TLP lost to 1 block/CU.
// Pipeline (hazard ledger, all derived):
//   3 LDS buffers (96KB), BK=32, stage distance 2: iter t reads buf[t%3],
//   stages tile t+2 into buf[(t+2)%3] (never aliased; t-1 readers are behind
//   the boundary barrier before buf[(t+2)%3]'s next reuse).
//   2 phases/tile: ph0 {stage A(t+2); ds_read A-quad0 + B; 16 MFMA} bar;
//                  ph1 {stage B(t+2); ds_read A-quad1 (B reg-reused); 16 MFMA}
//   boundary: vmcnt(4) retires t+1's 4 loads, leaves t+2's 4 IN FLIGHT across
//   the barrier (T4 counted-vmcnt); tail t+2>=KT: vmcnt(0) natural drain.
//   ds_reads are plain C++ -> compiler emits fine-grained lgkmcnt (no rule-18).
//   T5 setprio around MFMA clusters (phase-split structure = its valid regime).
// Swizzle: R2's proven XOR chunk scheme (0 conflicts measured): global chunk
//   (tid&3)^((tid>>3)&3) staged at linear tid slot; read at quad^((l15>>1)&3).
// Epilogue: identical per-(mt,nt) math to R2 (C frag: col=l15, row=quad*4+r).
// T1: XCD remap — each XCD owns 4 consecutive M-panels x all 12 N (A 2MB ~ L2).
__global__ __launch_bounds__(512, 2)
void gemm256(const u16* __restrict__ A, const u16* __restrict__ Bw,
             u16* __restrict__ oQ, u16* __restrict__ oK, u16* __restrict__ oVt,
             const float* __restrict__ ropeS, const float* __restrict__ ropeC) {
    __shared__ u16 As[3][256 * 32];     // 16KB per buffer
    __shared__ u16 Bs[3][256 * 32];     // 16KB per buffer
    const int tid  = threadIdx.x;
    const int wave = tid >> 6, lane = tid & 63;
    const int quad = lane >> 4, l15 = lane & 15;
    const int wr = wave >> 2, wc = wave & 3;    // wave tile: rows wr*128, cols wc*64
    // T1 remap: 384 blocks; xcd = lin&7; per XCD 4 M-panels x 12 N-panels
    const int lin = (int)blockIdx.x;
    const int xcd = lin & 7, idx = lin >> 3;          // idx in [0,48)
    const int mbase = (xcd * 4 + idx / 12) * 256;
    const int nbase = (idx % 12) * 256;

    f32x4 acc[8][4];
#pragma unroll
    for (int i = 0; i < 8; i++)
#pragma unroll
        for (int j = 0; j < 4; j++) acc[i][j] = (f32x4)0.0f;

    // staging: 512 threads, 4 threads/row -> 128 rows/round, 2 rounds per tile.
    // physical chunk (tid&3) holds global chunk (tid&3)^((srow>>1)&3)
    const int srow  = tid >> 2;                              // 0..127
    const int scolb = ((tid & 3) ^ ((tid >> 3) & 3)) * 16;   // byte offset
    const u16* gA = A  + (size_t)(mbase + srow) * KDIM;
    const u16* gB = Bw + (size_t)(nbase + srow) * KDIM;
    // fragment read: global chunk quad of row R at physical chunk quad^((l15>>1)&3)
    const int koffq = (quad ^ ((l15 >> 1) & 3)) * 8;         // u16 units

#define STAGE_A(ko, bufi) do {                                            \
        char* d_ = (char*)As[bufi] + tid * 16;                            \
        gl_lds16((const char*)(gA + (ko)) + scolb, d_);                   \
        gl_lds16((const char*)(gA + (ko) + (size_t)128 * KDIM) + scolb,   \
                 d_ + 8192);                                              \
    } while (0)
#define STAGE_B(ko, bufi) do {                                            \
        char* d_ = (char*)Bs[bufi] + tid * 16;                            \
        gl_lds16((const char*)(gB + (ko)) + scolb, d_);                   \
        gl_lds16((const char*)(gB + (ko) + (size_t)128 * KDIM) + scolb,   \
                 d_ + 8192);                                              \
    } while (0)

    const int KT = KDIM / 32;   // 32 K-tiles
    // prologue: tiles 0,1 into buffers 0,1; t0 retired, t1 in flight
    STAGE_A(0, 0);  STAGE_B(0, 0);
    STAGE_A(32, 1); STAGE_B(32, 1);
    wait_vm4();
    bar_raw();

    int cur = 0;
    for (int t = 0; t < KT; t++) {
        const bool pre = (t + 2 < KT);
        const int stg = (cur == 0) ? 2 : cur - 1;    // (cur+2)%3
        const int ko  = (t + 2) * 32;
        // ---- phase 0: stage A(t+2); compute quadrant mt=0..3 ----
        if (pre) STAGE_A(ko, stg);
        short8 af0[4], bfv[4];
#pragma unroll
        for (int mt = 0; mt < 4; mt++)
            af0[mt] = *(const short8*)&As[cur][(wr * 128 + mt * 16 + l15) * 32 + koffq];
#pragma unroll
        for (int nt = 0; nt < 4; nt++)
            bfv[nt] = *(const short8*)&Bs[cur][(wc * 64 + nt * 16 + l15) * 32 + koffq];
        __builtin_amdgcn_s_setprio(1);
#pragma unroll
        for (int mt = 0; mt < 4; mt++)
#pragma unroll
            for (int nt = 0; nt < 4; nt++)
                acc[mt][nt] = mfma_bf16(af0[mt], bfv[nt], acc[mt][nt]);
        __builtin_amdgcn_s_setprio(0);
        bar_raw();   // phase barrier (convoy alignment; no data hazard depends on it)
        // ---- phase 1: stage B(t+2); compute quadrant mt=4..7 (B reg-reused) ----
        if (pre) STAGE_B(ko, stg);
        short8 af1[4];
#pragma unroll
        for (int mt = 0; mt < 4; mt++)
            af1[mt] = *(const short8*)&As[cur][(wr * 128 + (4 + mt) * 16 + l15) * 32 + koffq];
        __builtin_amdgcn_s_setprio(1);
#pragma unroll
        for (int mt = 0; mt < 4; mt++)
#pragma unroll
            for (int nt = 0; nt < 4; nt++)
                acc[4 + mt][nt] = mfma_bf16(af1[mt], bfv[nt], acc[4 + mt][nt]);
        __builtin_amdgcn_s_setprio(0);
        // boundary: retire t+1's 4 loads; t+2's 4 stay in flight across barrier
        if (pre) wait_vm4(); else wait_vm0();
        bar_raw();
        cur = (cur == 2) ? 0 : cur + 1;
    }
#undef STAGE_A
#undef STAGE_B

    // ---- epilogue (identical math to R2). C frag: col=l15, row=quad*4+r ----
    const int proj_blk = nbase >> 10;   // block-uniform: 0=Q 1=K 2=V (256 | 1024)

    const float* sB[4];
    const float* cB[4];
    if (proj_blk < 2) {
#pragma unroll
        for (int nt = 0; nt < 4; nt++) {
            const int fi = nt * 8 + (l15 >> 1);
            sB[nt] = ropeS + fi * 2048;
            cB[nt] = ropeC + fi * 2048;
        }
    }
    const int par = l15 & 1;   // 0: even d (e-slot), 1: odd d (o-slot)

#pragma unroll
    for (int mt = 0; mt < 8; mt++) {
#pragma unroll
        for (int nt = 0; nt < 4; nt++) {
            const int n  = nbase + wc * 64 + nt * 16 + l15;
            const int mb = mbase + wr * 128 + mt * 16 + quad * 4;
            f32x4 v = acc[mt][nt];
            const int e = n & 1023;
            const int h = e >> 6, d = e & 63;
            if (proj_blk == 2) {
                const int b_ = mb >> 11, s = mb & 2047;
                const int bh = b_ * NHEAD + h;
                uint2 pk;                           // fp16 V (RTZ)
                pk.x = pk_f16(v[0], v[1]);
                pk.y = pk_f16(v[2], v[3]);
                *(uint2*)&oVt[((size_t)bh * DK + d) * S_LEN + s] = pk;
            } else {
                u16* dst = (proj_blk == 0) ? oQ : oK;
                float vp[4];
#pragma unroll
                for (int r = 0; r < 4; r++) vp[r] = __shfl_xor(v[r], 1);
                const int b_ = mb >> 11, s0 = mb & 2047;
                const int bh = b_ * NHEAD + h;
                const f32x4 sn = *(const f32x4*)(sB[nt] + s0);   // s0 % 4 == 0
                const f32x4 cs = *(const f32x4*)(cB[nt] + s0);
#pragma unroll
                for (int r = 0; r < 4; r++) {
                    const float res = par ? (vp[r] * sn[r] + v[r] * cs[r])
                                          : (v[r] * cs[r] - vp[r] * sn[r]);
                    dst[((size_t)bh * S_LEN + (s0 + r)) * DK + d] = f2bf(res);
                }
            }
        }
    }
}

// ---------- NT GEMM (exact R2 structure) — out-projection only ----------
// 128x128, 4 waves, 2-buffer raw-barrier pipeline; T1 remap (R5, neutral-harmless).
__global__ __launch_bounds__(256)
void gemm_nt1(const u16* __restrict__ A, const u16* __restrict__ Bw,
              float* __restrict__ oF) {
    __shared__ u16 As[2][128 * 32];
    __shared__ u16 Bs[2][128 * 32];
    const int tid  = threadIdx.x;
    const int wave = tid >> 6, lane = tid & 63;
    const int quad = lane >> 4, l15 = lane & 15;
    const int wr = wave >> 1, wc = wave & 1;
    const int NX  = 8;
    const int lin = (int)blockIdx.x + NX * (int)blockIdx.y;
    const int xcd = lin & 7, idx = lin >> 3;
    const int mbase = (xcd * 8 + idx / NX) * 128;
    const int nbase = (idx % NX) * 128;

    f32x4 acc[4][4];
#pragma unroll
    for (int i = 0; i < 4; i++)
#pragma unroll
        for (int j = 0; j < 4; j++) acc[i][j] = (f32x4)0.0f;

    const int srow0 = wave * 32 + (lane >> 2);
    const int srow1 = srow0 + 16;
    const int scolb = ((lane & 3) ^ ((lane >> 3) & 3)) * 16;
    const int ldsOff = wave * 2048 + lane * 16;         // bytes
    const u16* gA0 = A  + (size_t)(mbase + srow0) * KDIM;
    const u16* gA1 = A  + (size_t)(mbase + srow1) * KDIM;
    const u16* gB0 = Bw + (size_t)(nbase + srow0) * KDIM;
    const u16* gB1 = Bw + (size_t)(nbase + srow1) * KDIM;
    const int koffq = (quad ^ ((l15 >> 1) & 3)) * 8;    // u16 units

    gl_lds16((const char*)gA0 + scolb, (char*)As[0] + ldsOff);
    gl_lds16((const char*)gA1 + scolb, (char*)As[0] + ldsOff + 1024);
    gl_lds16((const char*)gB0 + scolb, (char*)Bs[0] + ldsOff);
    gl_lds16((const char*)gB1 + scolb, (char*)Bs[0] + ldsOff + 1024);

    const int KT = KDIM / 32;
    for (int kt = 0; kt < KT; kt++) {
        const int cur = kt & 1, nxt = cur ^ 1;
        const int kkn = ((kt + 1 < KT) ? (kt + 1) : kt) * 32;
        bar_raw();
        gl_lds16((const char*)(gA0 + kkn) + scolb, (char*)As[nxt] + ldsOff);
        gl_lds16((const char*)(gA1 + kkn) + scolb, (char*)As[nxt] + ldsOff + 1024);
        gl_lds16((const char*)(gB0 + kkn) + scolb, (char*)Bs[nxt] + ldsOff);
        gl_lds16((const char*)(gB1 + kkn) + scolb, (char*)Bs[nxt] + ldsOff + 1024);
        wait_vm4();
        bar_raw();

        short8 af[4], bf[4];
#pragma unroll
        for (int mt = 0; mt < 4; mt++)
            af[mt] = *(const short8*)&As[cur][(wr * 64 + mt * 16 + l15) * 32 + koffq];
#pragma unroll
        for (int nt = 0; nt < 4; nt++)
            bf[nt] = *(const short8*)&Bs[cur][(wc * 64 + nt * 16 + l15) * 32 + koffq];
#pragma unroll
        for (int mt = 0; mt < 4; mt++)
#pragma unroll
            for (int nt = 0; nt < 4; nt++)
                acc[mt][nt] = mfma_bf16(af[mt], bf[nt], acc[mt][nt]);
    }
    wait_vm0();

#pragma unroll
    for (int mt = 0; mt < 4; mt++) {
#pragma unroll
        for (int nt = 0; nt < 4; nt++) {
            const int n  = nbase + wc * 64 + nt * 16 + l15;
            const int mb = mbase + wr * 64 + mt * 16 + quad * 4;
            f32x4 v = acc[mt][nt];
#pragma unroll
            for (int r = 0; r < 4; r++)
                oF[(size_t)(mb + r) * DM + n] = v[r];
        }
    }
}

// ---------- causal flash attention (unchanged from R5: T1 remap + T5 setprio) ----------
__global__ __launch_bounds__(256)
void flash_attn(const u16* __restrict__ Q, const u16* __restrict__ K,
                const u16* __restrict__ Vt, u16* __restrict__ Oc) {
    __shared__ u16 Ks[2][64 * 64];     // permuted k-rows, XOR chunk swizzle
    __shared__ u16 Vs[2][64 * 64];     // [d][s], XOR chunk swizzle
    const int lin = (int)blockIdx.x + 64 * (int)blockIdx.y;   // [0,1024)
    const int xcd = lin & 7, idx = lin >> 3;                  // idx in [0,128)
    const int bh  = xcd * 8 + (idx & 7);
    const int qt  = 15 - (idx >> 3);
    const int tid  = threadIdx.x;
    const int wave = tid >> 6, lane = tid & 63;
    const int quad = lane >> 4, l15 = lane & 15;
    const int x7 = l15 & 7;
    const size_t headQK = (size_t)bh * S_LEN * DK;
    const size_t headVt = (size_t)bh * DK * S_LEN;
    const int b = bh >> 4, h = bh & 15;
    const float SCL = 0.18033688011112042f;   // (1/8) * log2(e)

    half8 ones;
#pragma unroll
    for (int j = 0; j < 8; j++) ones[j] = (_Float16)1.0f;

    const int rwl  = lane >> 3;                 // row within 8-row slab
    const int scol = (lane & 7) ^ rwl;          // XOR-swizzled chunk column
    const int rc0 = wave * 16 + rwl, rc1 = rc0 + 8;
    const u16* gK0 = K  + headQK + (size_t)perm_inv(rc0) * DK + scol * 8;
    const u16* gK1 = K  + headQK + (size_t)perm_inv(rc1) * DK + scol * 8;
    const u16* gV0 = Vt + headVt + (size_t)rc0 * S_LEN + scol * 8;
    const u16* gV1 = Vt + headVt + (size_t)rc1 * S_LEN + scol * 8;
    const int ldsOff = wave * 2048 + lane * 16;
    const int koff0 = (quad ^ x7) * 8;          // dk chunk 0..31, swizzled
    const int koff1 = ((4 + quad) ^ x7) * 8;    // dk chunk 32..63

    short8 qf[2][2];
#pragma unroll
    for (int hh = 0; hh < 2; hh++) {
        const int qrow = qt * 128 + hh * 64 + wave * 16 + l15;
        qf[hh][0] = *(const short8*)&Q[headQK + (size_t)qrow * DK + quad * 8];
        qf[hh][1] = *(const short8*)&Q[headQK + (size_t)qrow * DK + 32 + quad * 8];
    }

    float m_st[2];
    f32x4 lacc[2];
    f32x4 oacc[2][4];
#pragma unroll
    for (int hh = 0; hh < 2; hh++) {
        m_st[hh] = -__builtin_inff();
        lacc[hh] = (f32x4)0.0f;
#pragma unroll
        for (int n = 0; n < 4; n++) oacc[hh][n] = (f32x4)0.0f;
    }

    const int NT = 2 * qt + 2;
    gl_lds16(gK0, (char*)Ks[0] + ldsOff);
    gl_lds16(gK1, (char*)Ks[0] + ldsOff + 1024);
    gl_lds16(gV0, (char*)Vs[0] + ldsOff);
    gl_lds16(gV1, (char*)Vs[0] + ldsOff + 1024);

    for (int kt = 0; kt < NT; kt++) {
        const int cur = kt & 1, nxt = cur ^ 1;
        bar_raw();   // (A) everyone done reading buf[nxt]
        {            // prefetch tile kt+1 (clamped dummy on last iter)
            const int ktn = (kt + 1 < NT) ? kt + 1 : kt;
            gl_lds16(gK0 + (size_t)ktn * 64 * DK, (char*)Ks[nxt] + ldsOff);
            gl_lds16(gK1 + (size_t)ktn * 64 * DK, (char*)Ks[nxt] + ldsOff + 1024);
            gl_lds16(gV0 + ktn * 64,              (char*)Vs[nxt] + ldsOff);
            gl_lds16(gV1 + ktn * 64,              (char*)Vs[nxt] + ldsOff + 1024);
        }
        wait_vm4();  // tile kt landed; prefetch stays in flight
        bar_raw();   // (B) all waves' tile-kt staging visible

#pragma unroll
        for (int hh = 0; hh < 2; hh++) {
            if (hh == 0 && kt == 2 * qt + 1) continue;   // fully masked for half 0
            f32x4 sc[4];
            __builtin_amdgcn_s_setprio(1);
#pragma unroll
            for (int nt = 0; nt < 4; nt++) {
                const int rb = (nt * 16 + l15) * 64;
                short8 kf0 = *(const short8*)&Ks[cur][rb + koff0];
                short8 kf1 = *(const short8*)&Ks[cur][rb + koff1];
                f32x4 z = (f32x4)0.0f;
                z = mfma_bf16(kf0, qf[hh][0], z);
                z = mfma_bf16(kf1, qf[hh][1], z);
#pragma unroll
                for (int r = 0; r < 4; r++) z[r] *= SCL;
                sc[nt] = z;
            }
            __builtin_amdgcn_s_setprio(0);
            if (kt == 2 * qt + hh) {   // diagonal tile: local k' > wave*16 + l15
                const int qloc = wave * 16 + l15;
#pragma unroll
                for (int nt = 0; nt < 4; nt++) {
                    const int kb = 32 * (nt >> 1) + 8 * quad + 4 * (nt & 1);
#pragma unroll
                    for (int r = 0; r < 4; r++)
                        if (kb + r > qloc) sc[nt][r] = -__builtin_inff();
                }
            }
            float mx0 = fmaxf(fmaxf(sc[0][0], sc[0][1]), fmaxf(sc[0][2], sc[0][3]));
            float mx1 = fmaxf(fmaxf(sc[1][0], sc[1][1]), fmaxf(sc[1][2], sc[1][3]));
            float mx2 = fmaxf(fmaxf(sc[2][0], sc[2][1]), fmaxf(sc[2][2], sc[2][3]));
            float mx3 = fmaxf(fmaxf(sc[3][0], sc[3][1]), fmaxf(sc[3][2], sc[3][3]));
            float mx = fmaxf(fmaxf(mx0, mx1), fmaxf(mx2, mx3));
            mx = fmaxf(mx, __shfl_xor(mx, 16));
            mx = fmaxf(mx, __shfl_xor(mx, 32));
            const float mn = fmaxf(m_st[hh], mx);
            const float alpha = __builtin_amdgcn_exp2f(m_st[hh] - mn);
            m_st[hh] = mn;
#pragma unroll
            for (int nt = 0; nt < 4; nt++)
#pragma unroll
                for (int r = 0; r < 4; r++)
                    sc[nt][r] = __builtin_amdgcn_exp2f(sc[nt][r] - m_st[hh]);
            u32 pw[8];
            pw[0] = pk_f16(sc[0][0], sc[0][1]); pw[1] = pk_f16(sc[0][2], sc[0][3]);
            pw[2] = pk_f16(sc[1][0], sc[1][1]); pw[3] = pk_f16(sc[1][2], sc[1][3]);
            pw[4] = pk_f16(sc[2][0], sc[2][1]); pw[5] = pk_f16(sc[2][2], sc[2][3]);
            pw[6] = pk_f16(sc[3][0], sc[3][1]); pw[7] = pk_f16(sc[3][2], sc[3][3]);
            half8 pf0 = __builtin_bit_cast(half8, *(uint4*)&pw[0]);
            half8 pf1 = __builtin_bit_cast(half8, *(uint4*)&pw[4]);
            float alr[4];
#pragma unroll
            for (int r = 0; r < 4; r++) alr[r] = __shfl(alpha, quad * 20 + r);
#pragma unroll
            for (int n = 0; n < 4; n++)
#pragma unroll
                for (int r = 0; r < 4; r++) oacc[hh][n][r] *= alr[r];
#pragma unroll
            for (int r = 0; r < 4; r++) lacc[hh][r] *= alr[r];
            __builtin_amdgcn_s_setprio(1);
#pragma unroll
            for (int c = 0; c < 2; c++) {
                const half8 pf = c ? pf1 : pf0;
                lacc[hh] = mfma_f16(pf, ones, lacc[hh]);
                const int voff = ((c * 4 + quad) ^ x7) * 8;
#pragma unroll
                for (int nt2 = 0; nt2 < 4; nt2++) {
                    half8 vf = __builtin_bit_cast(half8,
                        *(const short8*)&Vs[cur][(nt2 * 16 + l15) * 64 + voff]);
                    oacc[hh][nt2] = mfma_f16(pf, vf, oacc[hh][nt2]);
                }
            }
            __builtin_amdgcn_s_setprio(0);
        }
    }
    wait_vm0();   // drain dangling dummy prefetch before exit

#pragma unroll
    for (int hh = 0; hh < 2; hh++) {
#pragma unroll
        for (int r = 0; r < 4; r++) {
            const float inv = 1.0f / lacc[hh][r];
            const int s = qt * 128 + hh * 64 + wave * 16 + quad * 4 + r;
#pragma unroll
            for (int nt2 = 0; nt2 < 4; nt2++)
                Oc[((size_t)(b * S_LEN + s)) * DM + h * 64 + nt2 * 16 + l15] =
                    f2bf(oacc[hh][nt2][r] * inv);
        }
    }
}

// ---------- workspace layout (u16 elements) ----------
#define OFF_XBF   ((size_t)0)
#define OFF_WCAT  ((size_t)8388608)
#define OFF_WO    ((size_t)11534336)
#define OFF_QB    ((size_t)12582912)
#define OFF_KB    ((size_t)20971520)
#define OFF_VT    ((size_t)29360128)
#define OFF_ROPE  ((size_t)37748736)   // 65536 fp32 sin + 65536 fp32 cos = 512 KB

extern "C" void kernel_launch(void* const* d_in, const int* in_sizes, int n_in,
                              void* d_out, int out_size, void* d_ws, size_t ws_size,
                              hipStream_t stream) {
    const float* x  = (const float*)d_in[0];
    const float* Wq = (const float*)d_in[1];
    const float* Wk = (const float*)d_in[2];
    const float* Wv = (const float*)d_in[3];
    const float* Wo = (const float*)d_in[4];
    u16* ws  = (u16*)d_ws;
    u16* XBF = ws + OFF_XBF;
    u16* WCA = ws + OFF_WCAT;
    u16* WOB = ws + OFF_WO;
    u16* QB  = ws + OFF_QB;
    u16* KB  = ws + OFF_KB;
    u16* VT  = ws + OFF_VT;
    float* ropeS = (float*)(ws + OFF_ROPE);
    float* ropeC = ropeS + 65536;
    u16* AT  = XBF;   // reuse

    cvt_all<<<12544, 256, 0, stream>>>((const float4*)x, (const float4*)Wq,
                                       (const float4*)Wk, (const float4*)Wv,
                                       (const float4*)Wo,
                                       (uint2*)XBF, (uint2*)WCA, (uint2*)WOB,
                                       ropeS, ropeC);

    gemm256<<<384, 512, 0, stream>>>(XBF, WCA, QB, KB, VT, ropeS, ropeC);
    flash_attn<<<dim3(64, 16), 256, 0, stream>>>(QB, KB, VT, AT);
    gemm_nt1<<<dim3(8, 64), 256, 0, stream>>>(AT, WOB, (float*)d_out);
}

// Round 7
// 269.851 us; speedup vs baseline: 1.0876x; 1.0876x over previous
//
#include <hip/hip_runtime.h>

typedef unsigned short u16;
typedef unsigned int   u32;

typedef short    short8 __attribute__((ext_vector_type(8)));
typedef __bf16   bf16x8 __attribute__((ext_vector_type(8)));
typedef _Float16 half8  __attribute__((ext_vector_type(8)));
typedef float    f32x4  __attribute__((ext_vector_type(4)));

#define S_LEN   2048
#define DM      1024
#define NHEAD   16
#define DK      64
#define KDIM    1024

// ---------- helpers ----------
__device__ __forceinline__ u16 f2bf(float f) {
    u32 u = __builtin_bit_cast(u32, f);
    u += 0x7FFFu + ((u >> 16) & 1u);      // RNE
    return (u16)(u >> 16);
}
__device__ __forceinline__ f32x4 mfma_bf16(short8 a, short8 b, f32x4 c) {
    return __builtin_amdgcn_mfma_f32_16x16x32_bf16(
        __builtin_bit_cast(bf16x8, a), __builtin_bit_cast(bf16x8, b), c, 0, 0, 0);
}
__device__ __forceinline__ f32x4 mfma_f16(half8 a, half8 b, f32x4 c) {
    return __builtin_amdgcn_mfma_f32_16x16x32_f16(a, b, c, 0, 0, 0);
}
__device__ __forceinline__ u32 pk_f16(float a, float b) {
    return __builtin_bit_cast(u32, __builtin_amdgcn_cvt_pkrtz(a, b));
}
__device__ __forceinline__ void gl_lds16(const void* g, void* l) {
    __builtin_amdgcn_global_load_lds(
        (const __attribute__((address_space(1))) u32*)g,
        (__attribute__((address_space(3))) u32*)l, 16, 0, 0);
}
// raw barrier / waitcnt: no compiler-inserted vmcnt(0) drain (prefetch stays in flight)
__device__ __forceinline__ void bar_raw() { asm volatile("s_barrier" ::: "memory"); }
__device__ __forceinline__ void wait_vm4() { asm volatile("s_waitcnt vmcnt(4)" ::: "memory"); }
__device__ __forceinline__ void wait_vm0() { asm volatile("s_waitcnt vmcnt(0)" ::: "memory"); }

// K-row permutation for flash: LDS row rc holds global k-row perm_inv(rc) so that
// PV A-frags are in-lane after S^T: k'(nt,quad,r)=32*(nt>>1)+8*quad+4*(nt&1)+r
__device__ __forceinline__ int perm_inv(int rc) {
    const int nt = rc >> 4, mid = (rc >> 2) & 3, r = rc & 3;
    return 32 * (nt >> 1) + 8 * mid + 4 * (nt & 1) + r;
}

// ---------- fused fp32->bf16 convert + RoPE table build ----------
__global__ void cvt_all(const float4* __restrict__ x,  const float4* __restrict__ Wq,
                        const float4* __restrict__ Wk, const float4* __restrict__ Wv,
                        const float4* __restrict__ Wo,
                        uint2* __restrict__ oX, uint2* __restrict__ oWcat,
                        uint2* __restrict__ oWo,
                        float* __restrict__ sT, float* __restrict__ cT) {
    const int i = blockIdx.x * 256 + threadIdx.x;
    if (i < 3145728) {
        const float4* in;
        uint2* out;
        if (i < 2097152) {
            in = x + i;  out = oX + i;
        } else {
            const int j = i - 2097152;
            const int w = j >> 18, k = j & 262143;
            in  = (w == 0 ? Wq : w == 1 ? Wk : w == 2 ? Wv : Wo) + k;
            out = (w < 3) ? (oWcat + w * 262144 + k) : (oWo + k);
        }
        float4 f = *in;
        uint2 o;
        o.x = (u32)f2bf(f.x) | ((u32)f2bf(f.y) << 16);
        o.y = (u32)f2bf(f.z) | ((u32)f2bf(f.w) << 16);
        *out = o;
    } else {
        const int idx = i - 3145728;            // [0, 65536): i=idx>>11, s=idx&2047
        const float fi = expf(-(float)(idx >> 11) * 0.287823136624255f);
        const float ang = (float)(idx & 2047) * fi;
        sT[idx] = sinf(ang);
        cT[idx] = cosf(ang);
    }
}

// ---------- NT GEMM (exact R5-measured structure, 92.1us): BM=BN=128, BK=32 ----------
// 2-buffer LDS, raw-barrier pipeline (no vmcnt(0) in loop), dist-1 prefetch.
// T1 XCD remap (R5: FETCH -4.5%, neutral-to-positive). R6: gemm256 reverted (113us,
// occupancy-collapsed; 2-phase family ceiling ~560 TF accepted for now).
// LDS XOR chunk swizzle: row r's chunk c at physical chunk c^((r>>1)&3) -> <=2-way banks.
// MODE 0: N=3072 fused QKV epilogue with table-based RoPE on Q,K; V fp16 transposed.
// MODE 1: plain fp32 store.
template <int MODE>
__global__ __launch_bounds__(256)
void gemm_nt(const u16* __restrict__ A, const u16* __restrict__ Bw,
             u16* __restrict__ oQ, u16* __restrict__ oK, u16* __restrict__ oVt,
             float* __restrict__ oF,
             const float* __restrict__ ropeS, const float* __restrict__ ropeC) {
    __shared__ u16 As[2][128 * 32];
    __shared__ u16 Bs[2][128 * 32];
    const int tid  = threadIdx.x;
    const int wave = tid >> 6, lane = tid & 63;
    const int quad = lane >> 4, l15 = lane & 15;
    const int wr = wave >> 1, wc = wave & 1;
    // T1 remap: lin -> (xcd, idx); y = xcd*8 + idx/NX, x = idx%NX
    const int NX  = (MODE == 0) ? 24 : 8;
    const int lin = (int)blockIdx.x + NX * (int)blockIdx.y;
    const int xcd = lin & 7, idx = lin >> 3;
    const int mbase = (xcd * 8 + idx / NX) * 128;
    const int nbase = (idx % NX) * 128;

    f32x4 acc[4][4];
#pragma unroll
    for (int i = 0; i < 4; i++)
#pragma unroll
        for (int j = 0; j < 4; j++) acc[i][j] = (f32x4)0.0f;

    // staging: physical chunk holds global chunk c = (lane&3)^((lane>>3)&3) of row srow
    const int srow0 = wave * 32 + (lane >> 2);
    const int srow1 = srow0 + 16;
    const int scolb = ((lane & 3) ^ ((lane >> 3) & 3)) * 16;
    const int ldsOff = wave * 2048 + lane * 16;         // bytes
    const u16* gA0 = A  + (size_t)(mbase + srow0) * KDIM;
    const u16* gA1 = A  + (size_t)(mbase + srow1) * KDIM;
    const u16* gB0 = Bw + (size_t)(nbase + srow0) * KDIM;
    const u16* gB1 = Bw + (size_t)(nbase + srow1) * KDIM;
    // fragment read: chunk quad of row R at physical chunk quad^((l15>>1)&3)
    const int koffq = (quad ^ ((l15 >> 1) & 3)) * 8;    // u16 units

    // prologue: stage tile 0 into buffer 0
    gl_lds16((const char*)gA0 + scolb, (char*)As[0] + ldsOff);
    gl_lds16((const char*)gA1 + scolb, (char*)As[0] + ldsOff + 1024);
    gl_lds16((const char*)gB0 + scolb, (char*)Bs[0] + ldsOff);
    gl_lds16((const char*)gB1 + scolb, (char*)Bs[0] + ldsOff + 1024);

    const int KT = KDIM / 32;
    for (int kt = 0; kt < KT; kt++) {
        const int cur = kt & 1, nxt = cur ^ 1;
        const int kkn = ((kt + 1 < KT) ? (kt + 1) : kt) * 32;
        bar_raw();   // (A) all waves done reading buf[nxt]
        gl_lds16((const char*)(gA0 + kkn) + scolb, (char*)As[nxt] + ldsOff);
        gl_lds16((const char*)(gA1 + kkn) + scolb, (char*)As[nxt] + ldsOff + 1024);
        gl_lds16((const char*)(gB0 + kkn) + scolb, (char*)Bs[nxt] + ldsOff);
        gl_lds16((const char*)(gB1 + kkn) + scolb, (char*)Bs[nxt] + ldsOff + 1024);
        wait_vm4();  // tile kt's 4 loads retired; prefetch still in flight
        bar_raw();   // (B) tile-kt staging visible to all waves

        short8 af[4], bf[4];
#pragma unroll
        for (int mt = 0; mt < 4; mt++)
            af[mt] = *(const short8*)&As[cur][(wr * 64 + mt * 16 + l15) * 32 + koffq];
#pragma unroll
        for (int nt = 0; nt < 4; nt++)
            bf[nt] = *(const short8*)&Bs[cur][(wc * 64 + nt * 16 + l15) * 32 + koffq];
#pragma unroll
        for (int mt = 0; mt < 4; mt++)
#pragma unroll
            for (int nt = 0; nt < 4; nt++)
                acc[mt][nt] = mfma_bf16(af[mt], bf[nt], acc[mt][nt]);
    }
    wait_vm0();   // drain dangling dummy prefetch

    // ---- epilogue. C layout: col = l15, row = quad*4 + reg ----
    const int proj_blk = (MODE == 0) ? (nbase >> 10) : 2;   // block-uniform: 0=Q 1=K 2=V

    const float* sB[4];
    const float* cB[4];
    if (MODE == 0 && proj_blk < 2) {
#pragma unroll
        for (int nt = 0; nt < 4; nt++) {
            const int fi = nt * 8 + (l15 >> 1);
            sB[nt] = ropeS + fi * 2048;
            cB[nt] = ropeC + fi * 2048;
        }
    }
    const int par = l15 & 1;   // 0: even d (e-slot), 1: odd d (o-slot)

#pragma unroll
    for (int mt = 0; mt < 4; mt++) {
#pragma unroll
        for (int nt = 0; nt < 4; nt++) {
            const int n  = nbase + wc * 64 + nt * 16 + l15;
            const int mb = mbase + wr * 64 + mt * 16 + quad * 4;
            f32x4 v = acc[mt][nt];
            if (MODE == 0) {
                const int e = n & 1023;
                const int h = e >> 6, d = e & 63;
                if (proj_blk == 2) {
                    const int b_ = mb >> 11, s = mb & 2047;
                    const int bh = b_ * NHEAD + h;
                    uint2 pk;                           // fp16 V (RTZ)
                    pk.x = pk_f16(v[0], v[1]);
                    pk.y = pk_f16(v[2], v[3]);
                    *(uint2*)&oVt[((size_t)bh * DK + d) * S_LEN + s] = pk;
                } else {
                    u16* dst = (proj_blk == 0) ? oQ : oK;
                    // partner values (d^1 lives in lane^1)
                    float vp[4];
#pragma unroll
                    for (int r = 0; r < 4; r++) vp[r] = __shfl_xor(v[r], 1);
                    const int b_ = mb >> 11, s0 = mb & 2047;
                    const int bh = b_ * NHEAD + h;
                    const f32x4 sn = *(const f32x4*)(sB[nt] + s0);   // s0 % 4 == 0
                    const f32x4 cs = *(const f32x4*)(cB[nt] + s0);
#pragma unroll
                    for (int r = 0; r < 4; r++) {
                        const float res = par ? (vp[r] * sn[r] + v[r] * cs[r])
                                              : (v[r] * cs[r] - vp[r] * sn[r]);
                        dst[((size_t)bh * S_LEN + (s0 + r)) * DK + d] = f2bf(res);
                    }
                }
            } else {
#pragma unroll
                for (int r = 0; r < 4; r++)
                    oF[(size_t)(mb + r) * DM + n] = v[r];
            }
        }
    }
}

// ---------- causal flash attention: 128-row Q-tiles, S^T form, P in-register ----------
// R6 change: K/V LDS-read dedup. kf/vf fragments depend only on (nt,cur)/(c,nt2,cur),
// NOT on the q-half hh — previously each wave read the full 8KB K and 8KB V tiles
// TWICE per iteration (32KB/wave-iter, ~2.2GB total = ~43us at 52 TB/s b128 rate).
// Now: QK reads kf once, feeds both halves' MFMAs; PV reads vf once, feeds both.
// Softmax math per-hh unchanged (bitwise-identical); half 0 skipped at its fully-
// masked iter kt==2qt+1 via uniform act0 guard (pf[0] only used under same guard).
// T1 XCD remap + T5 setprio kept from R5.
__global__ __launch_bounds__(256)
void flash_attn(const u16* __restrict__ Q, const u16* __restrict__ K,
                const u16* __restrict__ Vt, u16* __restrict__ Oc) {
    __shared__ u16 Ks[2][64 * 64];     // permuted k-rows, XOR chunk swizzle
    __shared__ u16 Vs[2][64 * 64];     // [d][s], XOR chunk swizzle
    const int lin = (int)blockIdx.x + 64 * (int)blockIdx.y;   // [0,1024)
    const int xcd = lin & 7, idx = lin >> 3;                  // idx in [0,128)
    const int bh  = xcd * 8 + (idx & 7);
    const int qt  = 15 - (idx >> 3);
    const int tid  = threadIdx.x;
    const int wave = tid >> 6, lane = tid & 63;
    const int quad = lane >> 4, l15 = lane & 15;
    const int x7 = l15 & 7;
    const size_t headQK = (size_t)bh * S_LEN * DK;
    const size_t headVt = (size_t)bh * DK * S_LEN;
    const int b = bh >> 4, h = bh & 15;
    const float SCL = 0.18033688011112042f;   // (1/8) * log2(e)

    half8 ones;
#pragma unroll
    for (int j = 0; j < 8; j++) ones[j] = (_Float16)1.0f;

    const int rwl  = lane >> 3;                 // row within 8-row slab
    const int scol = (lane & 7) ^ rwl;          // XOR-swizzled chunk column
    const int rc0 = wave * 16 + rwl, rc1 = rc0 + 8;
    const u16* gK0 = K  + headQK + (size_t)perm_inv(rc0) * DK + scol * 8;
    const u16* gK1 = K  + headQK + (size_t)perm_inv(rc1) * DK + scol * 8;
    const u16* gV0 = Vt + headVt + (size_t)rc0 * S_LEN + scol * 8;
    const u16* gV1 = Vt + headVt + (size_t)rc1 * S_LEN + scol * 8;
    const int ldsOff = wave * 2048 + lane * 16;
    const int koff0 = (quad ^ x7) * 8;          // dk chunk 0..31, swizzled
    const int koff1 = ((4 + quad) ^ x7) * 8;    // dk chunk 32..63

    short8 qf[2][2];
#pragma unroll
    for (int hh = 0; hh < 2; hh++) {
        const int qrow = qt * 128 + hh * 64 + wave * 16 + l15;
        qf[hh][0] = *(const short8*)&Q[headQK + (size_t)qrow * DK + quad * 8];
        qf[hh][1] = *(const short8*)&Q[headQK + (size_t)qrow * DK + 32 + quad * 8];
    }

    float m_st[2];
    f32x4 lacc[2];
    f32x4 oacc[2][4];
#pragma unroll
    for (int hh = 0; hh < 2; hh++) {
        m_st[hh] = -__builtin_inff();
        lacc[hh] = (f32x4)0.0f;
#pragma unroll
        for (int n = 0; n < 4; n++) oacc[hh][n] = (f32x4)0.0f;
    }

    const int NT = 2 * qt + 2;
    gl_lds16(gK0, (char*)Ks[0] + ldsOff);
    gl_lds16(gK1, (char*)Ks[0] + ldsOff + 1024);
    gl_lds16(gV0, (char*)Vs[0] + ldsOff);
    gl_lds16(gV1, (char*)Vs[0] + ldsOff + 1024);

    for (int kt = 0; kt < NT; kt++) {
        const int cur = kt & 1, nxt = cur ^ 1;
        bar_raw();   // (A) everyone done reading buf[nxt]
        {            // prefetch tile kt+1 (clamped dummy on last iter)
            const int ktn = (kt + 1 < NT) ? kt + 1 : kt;
            gl_lds16(gK0 + (size_t)ktn * 64 * DK, (char*)Ks[nxt] + ldsOff);
            gl_lds16(gK1 + (size_t)ktn * 64 * DK, (char*)Ks[nxt] + ldsOff + 1024);
            gl_lds16(gV0 + ktn * 64,              (char*)Vs[nxt] + ldsOff);
            gl_lds16(gV1 + ktn * 64,              (char*)Vs[nxt] + ldsOff + 1024);
        }
        wait_vm4();  // tile kt landed; prefetch stays in flight
        bar_raw();   // (B) all waves' tile-kt staging visible

        const bool act0 = (kt != 2 * qt + 1);   // half 0 fully masked at kt==2qt+1

        // ---- QK^T, both halves, K-frags read once ----
        f32x4 sc[2][4];
        __builtin_amdgcn_s_setprio(1);
#pragma unroll
        for (int nt = 0; nt < 4; nt++) {
            const int rb = (nt * 16 + l15) * 64;
            short8 kf0 = *(const short8*)&Ks[cur][rb + koff0];
            short8 kf1 = *(const short8*)&Ks[cur][rb + koff1];
            f32x4 z0 = (f32x4)0.0f, z1 = (f32x4)0.0f;
            z0 = mfma_bf16(kf0, qf[0][0], z0);
            z0 = mfma_bf16(kf1, qf[0][1], z0);
            z1 = mfma_bf16(kf0, qf[1][0], z1);
            z1 = mfma_bf16(kf1, qf[1][1], z1);
#pragma unroll
            for (int r = 0; r < 4; r++) { z0[r] *= SCL; z1[r] *= SCL; }
            sc[0][nt] = z0;
            sc[1][nt] = z1;
        }
        __builtin_amdgcn_s_setprio(0);

        // ---- softmax per half (math identical to pre-R6) ----
        half8 pf[2][2];
        float alr[2][4];
#pragma unroll
        for (int hh = 0; hh < 2; hh++) {
            if (hh == 0 && !act0) continue;
            if (kt == 2 * qt + hh) {   // diagonal tile: local k' > wave*16 + l15
                const int qloc = wave * 16 + l15;
#pragma unroll
                for (int nt = 0; nt < 4; nt++) {
                    const int kb = 32 * (nt >> 1) + 8 * quad + 4 * (nt & 1);
#pragma unroll
                    for (int r = 0; r < 4; r++)
                        if (kb + r > qloc) sc[hh][nt][r] = -__builtin_inff();
                }
            }
            float mx0 = fmaxf(fmaxf(sc[hh][0][0], sc[hh][0][1]), fmaxf(sc[hh][0][2], sc[hh][0][3]));
            float mx1 = fmaxf(fmaxf(sc[hh][1][0], sc[hh][1][1]), fmaxf(sc[hh][1][2], sc[hh][1][3]));
            float mx2 = fmaxf(fmaxf(sc[hh][2][0], sc[hh][2][1]), fmaxf(sc[hh][2][2], sc[hh][2][3]));
            float mx3 = fmaxf(fmaxf(sc[hh][3][0], sc[hh][3][1]), fmaxf(sc[hh][3][2], sc[hh][3][3]));
            float mx = fmaxf(fmaxf(mx0, mx1), fmaxf(mx2, mx3));
            mx = fmaxf(mx, __shfl_xor(mx, 16));
            mx = fmaxf(mx, __shfl_xor(mx, 32));
            const float mn = fmaxf(m_st[hh], mx);
            const float alpha = __builtin_amdgcn_exp2f(m_st[hh] - mn);
            m_st[hh] = mn;
#pragma unroll
            for (int nt = 0; nt < 4; nt++)
#pragma unroll
                for (int r = 0; r < 4; r++)
                    sc[hh][nt][r] = __builtin_amdgcn_exp2f(sc[hh][nt][r] - m_st[hh]);
            u32 pw[8];
            pw[0] = pk_f16(sc[hh][0][0], sc[hh][0][1]); pw[1] = pk_f16(sc[hh][0][2], sc[hh][0][3]);
            pw[2] = pk_f16(sc[hh][1][0], sc[hh][1][1]); pw[3] = pk_f16(sc[hh][1][2], sc[hh][1][3]);
            pw[4] = pk_f16(sc[hh][2][0], sc[hh][2][1]); pw[5] = pk_f16(sc[hh][2][2], sc[hh][2][3]);
            pw[6] = pk_f16(sc[hh][3][0], sc[hh][3][1]); pw[7] = pk_f16(sc[hh][3][2], sc[hh][3][3]);
            pf[hh][0] = __builtin_bit_cast(half8, *(uint4*)&pw[0]);
            pf[hh][1] = __builtin_bit_cast(half8, *(uint4*)&pw[4]);
            // alpha broadcast for C-layout rows quad*4+r (src lane = quad*16 + quad*4+r)
#pragma unroll
            for (int r = 0; r < 4; r++) alr[hh][r] = __shfl(alpha, quad * 20 + r);
#pragma unroll
            for (int n = 0; n < 4; n++)
#pragma unroll
                for (int r = 0; r < 4; r++) oacc[hh][n][r] *= alr[hh][r];
#pragma unroll
            for (int r = 0; r < 4; r++) lacc[hh][r] *= alr[hh][r];
        }

        // ---- PV + row-sum, both halves, V-frags read once ----
        __builtin_amdgcn_s_setprio(1);
#pragma unroll
        for (int c = 0; c < 2; c++) {
            if (act0) lacc[0] = mfma_f16(pf[0][c], ones, lacc[0]);
            lacc[1] = mfma_f16(pf[1][c], ones, lacc[1]);
            const int voff = ((c * 4 + quad) ^ x7) * 8;
#pragma unroll
            for (int nt2 = 0; nt2 < 4; nt2++) {
                half8 vf = __builtin_bit_cast(half8,
                    *(const short8*)&Vs[cur][(nt2 * 16 + l15) * 64 + voff]);
                if (act0) oacc[0][nt2] = mfma_f16(pf[0][c], vf, oacc[0][nt2]);
                oacc[1][nt2] = mfma_f16(pf[1][c], vf, oacc[1][nt2]);
            }
        }
        __builtin_amdgcn_s_setprio(0);
    }
    wait_vm0();   // drain dangling dummy prefetch before exit

#pragma unroll
    for (int hh = 0; hh < 2; hh++) {
#pragma unroll
        for (int r = 0; r < 4; r++) {
            const float inv = 1.0f / lacc[hh][r];
            const int s = qt * 128 + hh * 64 + wave * 16 + quad * 4 + r;
#pragma unroll
            for (int nt2 = 0; nt2 < 4; nt2++)
                Oc[((size_t)(b * S_LEN + s)) * DM + h * 64 + nt2 * 16 + l15] =
                    f2bf(oacc[hh][nt2][r] * inv);
        }
    }
}

// ---------- workspace layout (u16 elements) ----------
#define OFF_XBF   ((size_t)0)
#define OFF_WCAT  ((size_t)8388608)
#define OFF_WO    ((size_t)11534336)
#define OFF_QB    ((size_t)12582912)
#define OFF_KB    ((size_t)20971520)
#define OFF_VT    ((size_t)29360128)
#define OFF_ROPE  ((size_t)37748736)   // 65536 fp32 sin + 65536 fp32 cos = 512 KB

extern "C" void kernel_launch(void* const* d_in, const int* in_sizes, int n_in,
                              void* d_out, int out_size, void* d_ws, size_t ws_size,
                              hipStream_t stream) {
    const float* x  = (const float*)d_in[0];
    const float* Wq = (const float*)d_in[1];
    const float* Wk = (const float*)d_in[2];
    const float* Wv = (const float*)d_in[3];
    const float* Wo = (const float*)d_in[4];
    u16* ws  = (u16*)d_ws;
    u16* XBF = ws + OFF_XBF;
    u16* WCA = ws + OFF_WCAT;
    u16* WOB = ws + OFF_WO;
    u16* QB  = ws + OFF_QB;
    u16* KB  = ws + OFF_KB;
    u16* VT  = ws + OFF_VT;
    float* ropeS = (float*)(ws + OFF_ROPE);
    float* ropeC = ropeS + 65536;
    u16* AT  = XBF;   // reuse

    cvt_all<<<12544, 256, 0, stream>>>((const float4*)x, (const float4*)Wq,
                                       (const float4*)Wk, (const float4*)Wv,
                                       (const float4*)Wo,
                                       (uint2*)XBF, (uint2*)WCA, (uint2*)WOB,
                                       ropeS, ropeC);

    gemm_nt<0><<<dim3(24, 64), 256, 0, stream>>>(XBF, WCA, QB, KB, VT, nullptr,
                                                 ropeS, ropeC);
    flash_attn<<<dim3(64, 16), 256, 0, stream>>>(QB, KB, VT, AT);
    gemm_nt<1><<<dim3(8, 64), 256, 0, stream>>>(AT, WOB, nullptr, nullptr, nullptr,
                                                (float*)d_out, nullptr, nullptr);
}

// Round 8
// 266.762 us; speedup vs baseline: 1.1002x; 1.0116x over previous
//
#include <hip/hip_runtime.h>

typedef unsigned short u16;
typedef unsigned int   u32;

typedef short    short8 __attribute__((ext_vector_type(8)));
typedef __bf16   bf16x8 __attribute__((ext_vector_type(8)));
typedef _Float16 half8  __attribute__((ext_vector_type(8)));
typedef float    f32x4  __attribute__((ext_vector_type(4)));

#define S_LEN   2048
#define DM      1024
#define NHEAD   16
#define DK      64
#define KDIM    1024

// ---------- helpers ----------
__device__ __forceinline__ u16 f2bf(float f) {
    u32 u = __builtin_bit_cast(u32, f);
    u += 0x7FFFu + ((u >> 16) & 1u);      // RNE
    return (u16)(u >> 16);
}
__device__ __forceinline__ f32x4 mfma_bf16(short8 a, short8 b, f32x4 c) {
    return __builtin_amdgcn_mfma_f32_16x16x32_bf16(
        __builtin_bit_cast(bf16x8, a), __builtin_bit_cast(bf16x8, b), c, 0, 0, 0);
}
__device__ __forceinline__ f32x4 mfma_f16(half8 a, half8 b, f32x4 c) {
    return __builtin_amdgcn_mfma_f32_16x16x32_f16(a, b, c, 0, 0, 0);
}
__device__ __forceinline__ u32 pk_f16(float a, float b) {
    return __builtin_bit_cast(u32, __builtin_amdgcn_cvt_pkrtz(a, b));
}
__device__ __forceinline__ void gl_lds16(const void* g, void* l) {
    __builtin_amdgcn_global_load_lds(
        (const __attribute__((address_space(1))) u32*)g,
        (__attribute__((address_space(3))) u32*)l, 16, 0, 0);
}
// raw barrier / waitcnt (flash only): prefetch stays in flight across barrier
__device__ __forceinline__ void bar_raw() { asm volatile("s_barrier" ::: "memory"); }
__device__ __forceinline__ void wait_vm4() { asm volatile("s_waitcnt vmcnt(4)" ::: "memory"); }
__device__ __forceinline__ void wait_vm0() { asm volatile("s_waitcnt vmcnt(0)" ::: "memory"); }

// K-row permutation for flash: LDS row rc holds global k-row perm_inv(rc) so that
// PV A-frags are in-lane after S^T: k'(nt,quad,r)=32*(nt>>1)+8*quad+4*(nt&1)+r
__device__ __forceinline__ int perm_inv(int rc) {
    const int nt = rc >> 4, mid = (rc >> 2) & 3, r = rc & 3;
    return 32 * (nt >> 1) + 8 * mid + 4 * (nt & 1) + r;
}

// ---------- fused fp32->bf16 convert + RoPE table build ----------
__global__ void cvt_all(const float4* __restrict__ x,  const float4* __restrict__ Wq,
                        const float4* __restrict__ Wk, const float4* __restrict__ Wv,
                        const float4* __restrict__ Wo,
                        uint2* __restrict__ oX, uint2* __restrict__ oWcat,
                        uint2* __restrict__ oWo,
                        float* __restrict__ sT, float* __restrict__ cT) {
    const int i = blockIdx.x * 256 + threadIdx.x;
    if (i < 3145728) {
        const float4* in;
        uint2* out;
        if (i < 2097152) {
            in = x + i;  out = oX + i;
        } else {
            const int j = i - 2097152;
            const int w = j >> 18, k = j & 262143;
            in  = (w == 0 ? Wq : w == 1 ? Wk : w == 2 ? Wv : Wo) + k;
            out = (w < 3) ? (oWcat + w * 262144 + k) : (oWo + k);
        }
        float4 f = *in;
        uint2 o;
        o.x = (u32)f2bf(f.x) | ((u32)f2bf(f.y) << 16);
        o.y = (u32)f2bf(f.z) | ((u32)f2bf(f.w) << 16);
        *out = o;
    } else {
        const int idx = i - 3145728;            // [0, 65536): i=idx>>11, s=idx&2047
        const float fi = expf(-(float)(idx >> 11) * 0.287823136624255f);
        const float ang = (float)(idx & 2047) * fi;
        sT[idx] = sinf(ang);
        cT[idx] = cosf(ang);
    }
}

// ---------- NT GEMM, m97-exact structure (R7 redesign): BM=BN=128, BK=64 ----------
// R7 theory: our 563 TF vs m97's HW-proven 874-912 TF at the SAME 128^2 tile differs
// in BK (32 vs 64) and barrier style. m97: single-buffered 32KB LDS, __syncthreads
// pair (compiler emits vmcnt(0) drain), 32 MFMA per barrier-pair — overlap comes from
// ~3 blocks/CU cross-block TLP (m114), NOT intra-block pipelining (m131-141 neutral).
// This kernel = m97 with BK=64 stored as TWO 32-col sub-tiles, each using R2's proven
// conflict-free XOR chunk swizzle (naive 128B rows would be 8-way bank-conflicted;
// m97's linear layout measured 1.7e7 conflicts — we keep ~0).
// Per K-step: 8x gl_lds16 stage, sync(drain), 16x ds_read_b128, 32 MFMA.
// K-accumulation order identical to R2 (slice 0 then 1) -> bitwise-identical output.
// T1 XCD remap kept (R5: FETCH -4.5%).
// MODE 0: N=3072 fused QKV epilogue with table-based RoPE on Q,K; V fp16 transposed.
// MODE 1: plain fp32 store.
template <int MODE>
__global__ __launch_bounds__(256)
void gemm_nt(const u16* __restrict__ A, const u16* __restrict__ Bw,
             u16* __restrict__ oQ, u16* __restrict__ oK, u16* __restrict__ oVt,
             float* __restrict__ oF,
             const float* __restrict__ ropeS, const float* __restrict__ ropeC) {
    __shared__ u16 As[2][128 * 32];   // [k-slice][128 rows x 32 cols], single-buffered
    __shared__ u16 Bs[2][128 * 32];
    const int tid  = threadIdx.x;
    const int wave = tid >> 6, lane = tid & 63;
    const int quad = lane >> 4, l15 = lane & 15;
    const int wr = wave >> 1, wc = wave & 1;
    // T1 remap: lin -> (xcd, idx); y = xcd*8 + idx/NX, x = idx%NX
    const int NX  = (MODE == 0) ? 24 : 8;
    const int lin = (int)blockIdx.x + NX * (int)blockIdx.y;
    const int xcd = lin & 7, idx = lin >> 3;
    const int mbase = (xcd * 8 + idx / NX) * 128;
    const int nbase = (idx % NX) * 128;

    f32x4 acc[4][4];
#pragma unroll
    for (int i = 0; i < 4; i++)
#pragma unroll
        for (int j = 0; j < 4; j++) acc[i][j] = (f32x4)0.0f;

    // staging (per 32-col sub-tile, R2-proven): physical chunk (lane&3) of row srow
    // holds global chunk (lane&3)^((srow>>1)&3); 2 row-blocks (srow, srow+16)/call pair
    const int srow0 = wave * 32 + (lane >> 2);
    const int srow1 = srow0 + 16;
    const int scolb = ((lane & 3) ^ ((lane >> 3) & 3)) * 16;   // bytes within 64B subrow
    const int ldsOff = wave * 2048 + lane * 16;                // bytes
    const u16* gA0 = A  + (size_t)(mbase + srow0) * KDIM;
    const u16* gA1 = A  + (size_t)(mbase + srow1) * KDIM;
    const u16* gB0 = Bw + (size_t)(nbase + srow0) * KDIM;
    const u16* gB1 = Bw + (size_t)(nbase + srow1) * KDIM;
    // fragment read: chunk quad of row R at physical chunk quad^((l15>>1)&3)
    const int koffq = (quad ^ ((l15 >> 1) & 3)) * 8;    // u16 units

    const int KT = KDIM / 64;   // 16 K-steps
    for (int kt = 0; kt < KT; kt++) {
        const int kk = kt * 64;
        __syncthreads();   // all waves done reading previous tile's LDS
#pragma unroll
        for (int s = 0; s < 2; s++) {
            const int ko = kk + s * 32;
            gl_lds16((const char*)(gA0 + ko) + scolb, (char*)As[s] + ldsOff);
            gl_lds16((const char*)(gA1 + ko) + scolb, (char*)As[s] + ldsOff + 1024);
            gl_lds16((const char*)(gB0 + ko) + scolb, (char*)Bs[s] + ldsOff);
            gl_lds16((const char*)(gB1 + ko) + scolb, (char*)Bs[s] + ldsOff + 1024);
        }
        __syncthreads();   // compiler emits s_waitcnt vmcnt(0) drain before s_barrier

        short8 af[4][2], bf[4][2];
#pragma unroll
        for (int s = 0; s < 2; s++) {
#pragma unroll
            for (int mt = 0; mt < 4; mt++)
                af[mt][s] = *(const short8*)&As[s][(wr * 64 + mt * 16 + l15) * 32 + koffq];
#pragma unroll
            for (int nt = 0; nt < 4; nt++)
                bf[nt][s] = *(const short8*)&Bs[s][(wc * 64 + nt * 16 + l15) * 32 + koffq];
        }
#pragma unroll
        for (int s = 0; s < 2; s++)
#pragma unroll
            for (int mt = 0; mt < 4; mt++)
#pragma unroll
                for (int nt = 0; nt < 4; nt++)
                    acc[mt][nt] = mfma_bf16(af[mt][s], bf[nt][s], acc[mt][nt]);
    }

    // ---- epilogue. C layout: col = l15, row = quad*4 + reg ----
    const int proj_blk = (MODE == 0) ? (nbase >> 10) : 2;   // block-uniform: 0=Q 1=K 2=V

    const float* sB[4];
    const float* cB[4];
    if (MODE == 0 && proj_blk < 2) {
#pragma unroll
        for (int nt = 0; nt < 4; nt++) {
            const int fi = nt * 8 + (l15 >> 1);
            sB[nt] = ropeS + fi * 2048;
            cB[nt] = ropeC + fi * 2048;
        }
    }
    const int par = l15 & 1;   // 0: even d (e-slot), 1: odd d (o-slot)

#pragma unroll
    for (int mt = 0; mt < 4; mt++) {
#pragma unroll
        for (int nt = 0; nt < 4; nt++) {
            const int n  = nbase + wc * 64 + nt * 16 + l15;
            const int mb = mbase + wr * 64 + mt * 16 + quad * 4;
            f32x4 v = acc[mt][nt];
            if (MODE == 0) {
                const int e = n & 1023;
                const int h = e >> 6, d = e & 63;
                if (proj_blk == 2) {
                    const int b_ = mb >> 11, s = mb & 2047;
                    const int bh = b_ * NHEAD + h;
                    uint2 pk;                           // fp16 V (RTZ)
                    pk.x = pk_f16(v[0], v[1]);
                    pk.y = pk_f16(v[2], v[3]);
                    *(uint2*)&oVt[((size_t)bh * DK + d) * S_LEN + s] = pk;
                } else {
                    u16* dst = (proj_blk == 0) ? oQ : oK;
                    // partner values (d^1 lives in lane^1)
                    float vp[4];
#pragma unroll
                    for (int r = 0; r < 4; r++) vp[r] = __shfl_xor(v[r], 1);
                    const int b_ = mb >> 11, s0 = mb & 2047;
                    const int bh = b_ * NHEAD + h;
                    const f32x4 sn = *(const f32x4*)(sB[nt] + s0);   // s0 % 4 == 0
                    const f32x4 cs = *(const f32x4*)(cB[nt] + s0);
#pragma unroll
                    for (int r = 0; r < 4; r++) {
                        const float res = par ? (vp[r] * sn[r] + v[r] * cs[r])
                                              : (v[r] * cs[r] - vp[r] * sn[r]);
                        dst[((size_t)bh * S_LEN + (s0 + r)) * DK + d] = f2bf(res);
                    }
                }
            } else {
#pragma unroll
                for (int r = 0; r < 4; r++)
                    oF[(size_t)(mb + r) * DM + n] = v[r];
            }
        }
    }
}

// ---------- causal flash attention (unchanged from R6/R7 banked config) ----------
// K/V LDS-read dedup (R6, ~neutral), T1 XCD remap, T5 setprio.
__global__ __launch_bounds__(256)
void flash_attn(const u16* __restrict__ Q, const u16* __restrict__ K,
                const u16* __restrict__ Vt, u16* __restrict__ Oc) {
    __shared__ u16 Ks[2][64 * 64];     // permuted k-rows, XOR chunk swizzle
    __shared__ u16 Vs[2][64 * 64];     // [d][s], XOR chunk swizzle
    const int lin = (int)blockIdx.x + 64 * (int)blockIdx.y;   // [0,1024)
    const int xcd = lin & 7, idx = lin >> 3;                  // idx in [0,128)
    const int bh  = xcd * 8 + (idx & 7);
    const int qt  = 15 - (idx >> 3);
    const int tid  = threadIdx.x;
    const int wave = tid >> 6, lane = tid & 63;
    const int quad = lane >> 4, l15 = lane & 15;
    const int x7 = l15 & 7;
    const size_t headQK = (size_t)bh * S_LEN * DK;
    const size_t headVt = (size_t)bh * DK * S_LEN;
    const int b = bh >> 4, h = bh & 15;
    const float SCL = 0.18033688011112042f;   // (1/8) * log2(e)

    half8 ones;
#pragma unroll
    for (int j = 0; j < 8; j++) ones[j] = (_Float16)1.0f;

    const int rwl  = lane >> 3;                 // row within 8-row slab
    const int scol = (lane & 7) ^ rwl;          // XOR-swizzled chunk column
    const int rc0 = wave * 16 + rwl, rc1 = rc0 + 8;
    const u16* gK0 = K  + headQK + (size_t)perm_inv(rc0) * DK + scol * 8;
    const u16* gK1 = K  + headQK + (size_t)perm_inv(rc1) * DK + scol * 8;
    const u16* gV0 = Vt + headVt + (size_t)rc0 * S_LEN + scol * 8;
    const u16* gV1 = Vt + headVt + (size_t)rc1 * S_LEN + scol * 8;
    const int ldsOff = wave * 2048 + lane * 16;
    const int koff0 = (quad ^ x7) * 8;          // dk chunk 0..31, swizzled
    const int koff1 = ((4 + quad) ^ x7) * 8;    // dk chunk 32..63

    short8 qf[2][2];
#pragma unroll
    for (int hh = 0; hh < 2; hh++) {
        const int qrow = qt * 128 + hh * 64 + wave * 16 + l15;
        qf[hh][0] = *(const short8*)&Q[headQK + (size_t)qrow * DK + quad * 8];
        qf[hh][1] = *(const short8*)&Q[headQK + (size_t)qrow * DK + 32 + quad * 8];
    }

    float m_st[2];
    f32x4 lacc[2];
    f32x4 oacc[2][4];
#pragma unroll
    for (int hh = 0; hh < 2; hh++) {
        m_st[hh] = -__builtin_inff();
        lacc[hh] = (f32x4)0.0f;
#pragma unroll
        for (int n = 0; n < 4; n++) oacc[hh][n] = (f32x4)0.0f;
    }

    const int NT = 2 * qt + 2;
    gl_lds16(gK0, (char*)Ks[0] + ldsOff);
    gl_lds16(gK1, (char*)Ks[0] + ldsOff + 1024);
    gl_lds16(gV0, (char*)Vs[0] + ldsOff);
    gl_lds16(gV1, (char*)Vs[0] + ldsOff + 1024);

    for (int kt = 0; kt < NT; kt++) {
        const int cur = kt & 1, nxt = cur ^ 1;
        bar_raw();   // (A) everyone done reading buf[nxt]
        {            // prefetch tile kt+1 (clamped dummy on last iter)
            const int ktn = (kt + 1 < NT) ? kt + 1 : kt;
            gl_lds16(gK0 + (size_t)ktn * 64 * DK, (char*)Ks[nxt] + ldsOff);
            gl_lds16(gK1 + (size_t)ktn * 64 * DK, (char*)Ks[nxt] + ldsOff + 1024);
            gl_lds16(gV0 + ktn * 64,              (char*)Vs[nxt] + ldsOff);
            gl_lds16(gV1 + ktn * 64,              (char*)Vs[nxt] + ldsOff + 1024);
        }
        wait_vm4();  // tile kt landed; prefetch stays in flight
        bar_raw();   // (B) all waves' tile-kt staging visible

        const bool act0 = (kt != 2 * qt + 1);   // half 0 fully masked at kt==2qt+1

        // ---- QK^T, both halves, K-frags read once ----
        f32x4 sc[2][4];
        __builtin_amdgcn_s_setprio(1);
#pragma unroll
        for (int nt = 0; nt < 4; nt++) {
            const int rb = (nt * 16 + l15) * 64;
            short8 kf0 = *(const short8*)&Ks[cur][rb + koff0];
            short8 kf1 = *(const short8*)&Ks[cur][rb + koff1];
            f32x4 z0 = (f32x4)0.0f, z1 = (f32x4)0.0f;
            z0 = mfma_bf16(kf0, qf[0][0], z0);
            z0 = mfma_bf16(kf1, qf[0][1], z0);
            z1 = mfma_bf16(kf0, qf[1][0], z1);
            z1 = mfma_bf16(kf1, qf[1][1], z1);
#pragma unroll
            for (int r = 0; r < 4; r++) { z0[r] *= SCL; z1[r] *= SCL; }
            sc[0][nt] = z0;
            sc[1][nt] = z1;
        }
        __builtin_amdgcn_s_setprio(0);

        // ---- softmax per half (math identical to pre-R6) ----
        half8 pf[2][2];
        float alr[2][4];
#pragma unroll
        for (int hh = 0; hh < 2; hh++) {
            if (hh == 0 && !act0) continue;
            if (kt == 2 * qt + hh) {   // diagonal tile: local k' > wave*16 + l15
                const int qloc = wave * 16 + l15;
#pragma unroll
                for (int nt = 0; nt < 4; nt++) {
                    const int kb = 32 * (nt >> 1) + 8 * quad + 4 * (nt & 1);
#pragma unroll
                    for (int r = 0; r < 4; r++)
                        if (kb + r > qloc) sc[hh][nt][r] = -__builtin_inff();
                }
            }
            float mx0 = fmaxf(fmaxf(sc[hh][0][0], sc[hh][0][1]), fmaxf(sc[hh][0][2], sc[hh][0][3]));
            float mx1 = fmaxf(fmaxf(sc[hh][1][0], sc[hh][1][1]), fmaxf(sc[hh][1][2], sc[hh][1][3]));
            float mx2 = fmaxf(fmaxf(sc[hh][2][0], sc[hh][2][1]), fmaxf(sc[hh][2][2], sc[hh][2][3]));
            float mx3 = fmaxf(fmaxf(sc[hh][3][0], sc[hh][3][1]), fmaxf(sc[hh][3][2], sc[hh][3][3]));
            float mx = fmaxf(fmaxf(mx0, mx1), fmaxf(mx2, mx3));
            mx = fmaxf(mx, __shfl_xor(mx, 16));
            mx = fmaxf(mx, __shfl_xor(mx, 32));
            const float mn = fmaxf(m_st[hh], mx);
            const float alpha = __builtin_amdgcn_exp2f(m_st[hh] - mn);
            m_st[hh] = mn;
#pragma unroll
            for (int nt = 0; nt < 4; nt++)
#pragma unroll
                for (int r = 0; r < 4; r++)
                    sc[hh][nt][r] = __builtin_amdgcn_exp2f(sc[hh][nt][r] - m_st[hh]);
            u32 pw[8];
            pw[0] = pk_f16(sc[hh][0][0], sc[hh][0][1]); pw[1] = pk_f16(sc[hh][0][2], sc[hh][0][3]);
            pw[2] = pk_f16(sc[hh][1][0], sc[hh][1][1]); pw[3] = pk_f16(sc[hh][1][2], sc[hh][1][3]);
            pw[4] = pk_f16(sc[hh][2][0], sc[hh][2][1]); pw[5] = pk_f16(sc[hh][2][2], sc[hh][2][3]);
            pw[6] = pk_f16(sc[hh][3][0], sc[hh][3][1]); pw[7] = pk_f16(sc[hh][3][2], sc[hh][3][3]);
            pf[hh][0] = __builtin_bit_cast(half8, *(uint4*)&pw[0]);
            pf[hh][1] = __builtin_bit_cast(half8, *(uint4*)&pw[4]);
            // alpha broadcast for C-layout rows quad*4+r (src lane = quad*16 + quad*4+r)
#pragma unroll
            for (int r = 0; r < 4; r++) alr[hh][r] = __shfl(alpha, quad * 20 + r);
#pragma unroll
            for (int n = 0; n < 4; n++)
#pragma unroll
                for (int r = 0; r < 4; r++) oacc[hh][n][r] *= alr[hh][r];
#pragma unroll
            for (int r = 0; r < 4; r++) lacc[hh][r] *= alr[hh][r];
        }

        // ---- PV + row-sum, both halves, V-frags read once ----
        __builtin_amdgcn_s_setprio(1);
#pragma unroll
        for (int c = 0; c < 2; c++) {
            if (act0) lacc[0] = mfma_f16(pf[0][c], ones, lacc[0]);
            lacc[1] = mfma_f16(pf[1][c], ones, lacc[1]);
            const int voff = ((c * 4 + quad) ^ x7) * 8;
#pragma unroll
            for (int nt2 = 0; nt2 < 4; nt2++) {
                half8 vf = __builtin_bit_cast(half8,
                    *(const short8*)&Vs[cur][(nt2 * 16 + l15) * 64 + voff]);
                if (act0) oacc[0][nt2] = mfma_f16(pf[0][c], vf, oacc[0][nt2]);
                oacc[1][nt2] = mfma_f16(pf[1][c], vf, oacc[1][nt2]);
            }
        }
        __builtin_amdgcn_s_setprio(0);
    }
    wait_vm0();   // drain dangling dummy prefetch before exit

#pragma unroll
    for (int hh = 0; hh < 2; hh++) {
#pragma unroll
        for (int r = 0; r < 4; r++) {
            const float inv = 1.0f / lacc[hh][r];
            const int s = qt * 128 + hh * 64 + wave * 16 + quad * 4 + r;
#pragma unroll
            for (int nt2 = 0; nt2 < 4; nt2++)
                Oc[((size_t)(b * S_LEN + s)) * DM + h * 64 + nt2 * 16 + l15] =
                    f2bf(oacc[hh][nt2][r] * inv);
        }
    }
}

// ---------- workspace layout (u16 elements) ----------
#define OFF_XBF   ((size_t)0)
#define OFF_WCAT  ((size_t)8388608)
#define OFF_WO    ((size_t)11534336)
#define OFF_QB    ((size_t)12582912)
#define OFF_KB    ((size_t)20971520)
#define OFF_VT    ((size_t)29360128)
#define OFF_ROPE  ((size_t)37748736)   // 65536 fp32 sin + 65536 fp32 cos = 512 KB

extern "C" void kernel_launch(void* const* d_in, const int* in_sizes, int n_in,
                              void* d_out, int out_size, void* d_ws, size_t ws_size,
                              hipStream_t stream) {
    const float* x  = (const float*)d_in[0];
    const float* Wq = (const float*)d_in[1];
    const float* Wk = (const float*)d_in[2];
    const float* Wv = (const float*)d_in[3];
    const float* Wo = (const float*)d_in[4];
    u16* ws  = (u16*)d_ws;
    u16* XBF = ws + OFF_XBF;
    u16* WCA = ws + OFF_WCAT;
    u16* WOB = ws + OFF_WO;
    u16* QB  = ws + OFF_QB;
    u16* KB  = ws + OFF_KB;
    u16* VT  = ws + OFF_VT;
    float* ropeS = (float*)(ws + OFF_ROPE);
    float* ropeC = ropeS + 65536;
    u16* AT  = XBF;   // reuse

    cvt_all<<<12544, 256, 0, stream>>>((const float4*)x, (const float4*)Wq,
                                       (const float4*)Wk, (const float4*)Wv,
                                       (const float4*)Wo,
                                       (uint2*)XBF, (uint2*)WCA, (uint2*)WOB,
                                       ropeS, ropeC);

    gemm_nt<0><<<dim3(24, 64), 256, 0, stream>>>(XBF, WCA, QB, KB, VT, nullptr,
                                                 ropeS, ropeC);
    flash_attn<<<dim3(64, 16), 256, 0, stream>>>(QB, KB, VT, AT);
    gemm_nt<1><<<dim3(8, 64), 256, 0, stream>>>(AT, WOB, nullptr, nullptr, nullptr,
                                                (float*)d_out, nullptr, nullptr);
}

// Round 9
// 263.892 us; speedup vs baseline: 1.1122x; 1.0109x over previous
//
#include <hip/hip_runtime.h>

typedef unsigned short u16;
typedef unsigned int   u32;

typedef short    short8 __attribute__((ext_vector_type(8)));
typedef __bf16   bf16x8 __attribute__((ext_vector_type(8)));
typedef _Float16 half8  __attribute__((ext_vector_type(8)));
typedef float    f32x4  __attribute__((ext_vector_type(4)));

#define S_LEN   2048
#define DM      1024
#define NHEAD   16
#define DK      64
#define KDIM    1024

// ---------- helpers ----------
__device__ __forceinline__ u16 f2bf(float f) {
    u32 u = __builtin_bit_cast(u32, f);
    u += 0x7FFFu + ((u >> 16) & 1u);      // RNE
    return (u16)(u >> 16);
}
__device__ __forceinline__ f32x4 mfma_bf16(short8 a, short8 b, f32x4 c) {
    return __builtin_amdgcn_mfma_f32_16x16x32_bf16(
        __builtin_bit_cast(bf16x8, a), __builtin_bit_cast(bf16x8, b), c, 0, 0, 0);
}
__device__ __forceinline__ f32x4 mfma_f16(half8 a, half8 b, f32x4 c) {
    return __builtin_amdgcn_mfma_f32_16x16x32_f16(a, b, c, 0, 0, 0);
}
__device__ __forceinline__ u32 pk_f16(float a, float b) {
    return __builtin_bit_cast(u32, __builtin_amdgcn_cvt_pkrtz(a, b));
}
__device__ __forceinline__ void gl_lds16(const void* g, void* l) {
    __builtin_amdgcn_global_load_lds(
        (const __attribute__((address_space(1))) u32*)g,
        (__attribute__((address_space(3))) u32*)l, 16, 0, 0);
}
// raw barrier / waitcnt (flash only): prefetch stays in flight across barrier
__device__ __forceinline__ void bar_raw() { asm volatile("s_barrier" ::: "memory"); }
__device__ __forceinline__ void wait_vm4() { asm volatile("s_waitcnt vmcnt(4)" ::: "memory"); }
__device__ __forceinline__ void wait_vm0() { asm volatile("s_waitcnt vmcnt(0)" ::: "memory"); }

// K-row permutation for flash: LDS row rc holds global k-row perm_inv(rc) so that
// PV A-frags are in-lane after S^T: k'(nt,quad,r)=32*(nt>>1)+8*quad+4*(nt&1)+r
__device__ __forceinline__ int perm_inv(int rc) {
    const int nt = rc >> 4, mid = (rc >> 2) & 3, r = rc & 3;
    return 32 * (nt >> 1) + 8 * mid + 4 * (nt & 1) + r;
}

// ---------- fused fp32->bf16 convert + RoPE table build ----------
__global__ void cvt_all(const float4* __restrict__ x,  const float4* __restrict__ Wq,
                        const float4* __restrict__ Wk, const float4* __restrict__ Wv,
                        const float4* __restrict__ Wo,
                        uint2* __restrict__ oX, uint2* __restrict__ oWcat,
                        uint2* __restrict__ oWo,
                        float* __restrict__ sT, float* __restrict__ cT) {
    const int i = blockIdx.x * 256 + threadIdx.x;
    if (i < 3145728) {
        const float4* in;
        uint2* out;
        if (i < 2097152) {
            in = x + i;  out = oX + i;
        } else {
            const int j = i - 2097152;
            const int w = j >> 18, k = j & 262143;
            in  = (w == 0 ? Wq : w == 1 ? Wk : w == 2 ? Wv : Wo) + k;
            out = (w < 3) ? (oWcat + w * 262144 + k) : (oWo + k);
        }
        float4 f = *in;
        uint2 o;
        o.x = (u32)f2bf(f.x) | ((u32)f2bf(f.y) << 16);
        o.y = (u32)f2bf(f.z) | ((u32)f2bf(f.w) << 16);
        *out = o;
    } else {
        const int idx = i - 3145728;            // [0, 65536): i=idx>>11, s=idx&2047
        const float fi = expf(-(float)(idx >> 11) * 0.287823136624255f);
        const float ang = (float)(idx & 2047) * fi;
        sT[idx] = sinf(ang);
        cT[idx] = cosf(ang);
    }
}

// ---------- NT GEMM, m97-exact structure (R7, banked 89.1us): BM=BN=128, BK=64 ----------
// Single-buffered 32KB LDS, __syncthreads pair (compiler emits vmcnt(0) drain),
// 32 MFMA per barrier-pair, cross-block TLP provides the overlap (m114).
// BK=64 as TWO 32-col sub-tiles, each with R2's conflict-free XOR chunk swizzle.
// After 5 schedule variants {92,97,113,90.5,89.1} this is the best; K=1024 shape
// pins the 128^2 family at ~570 TF (m102 shape curve) — GEMM lever exhausted.
// T1 XCD remap kept. MODE 0: QKV+RoPE epilogue; MODE 1: fp32 store.
template <int MODE>
__global__ __launch_bounds__(256)
void gemm_nt(const u16* __restrict__ A, const u16* __restrict__ Bw,
             u16* __restrict__ oQ, u16* __restrict__ oK, u16* __restrict__ oVt,
             float* __restrict__ oF,
             const float* __restrict__ ropeS, const float* __restrict__ ropeC) {
    __shared__ u16 As[2][128 * 32];   // [k-slice][128 rows x 32 cols], single-buffered
    __shared__ u16 Bs[2][128 * 32];
    const int tid  = threadIdx.x;
    const int wave = tid >> 6, lane = tid & 63;
    const int quad = lane >> 4, l15 = lane & 15;
    const int wr = wave >> 1, wc = wave & 1;
    // T1 remap: lin -> (xcd, idx); y = xcd*8 + idx/NX, x = idx%NX
    const int NX  = (MODE == 0) ? 24 : 8;
    const int lin = (int)blockIdx.x + NX * (int)blockIdx.y;
    const int xcd = lin & 7, idx = lin >> 3;
    const int mbase = (xcd * 8 + idx / NX) * 128;
    const int nbase = (idx % NX) * 128;

    f32x4 acc[4][4];
#pragma unroll
    for (int i = 0; i < 4; i++)
#pragma unroll
        for (int j = 0; j < 4; j++) acc[i][j] = (f32x4)0.0f;

    // staging (per 32-col sub-tile, R2-proven): physical chunk (lane&3) of row srow
    // holds global chunk (lane&3)^((srow>>1)&3); 2 row-blocks (srow, srow+16)/call pair
    const int srow0 = wave * 32 + (lane >> 2);
    const int srow1 = srow0 + 16;
    const int scolb = ((lane & 3) ^ ((lane >> 3) & 3)) * 16;   // bytes within 64B subrow
    const int ldsOff = wave * 2048 + lane * 16;                // bytes
    const u16* gA0 = A  + (size_t)(mbase + srow0) * KDIM;
    const u16* gA1 = A  + (size_t)(mbase + srow1) * KDIM;
    const u16* gB0 = Bw + (size_t)(nbase + srow0) * KDIM;
    const u16* gB1 = Bw + (size_t)(nbase + srow1) * KDIM;
    // fragment read: chunk quad of row R at physical chunk quad^((l15>>1)&3)
    const int koffq = (quad ^ ((l15 >> 1) & 3)) * 8;    // u16 units

    const int KT = KDIM / 64;   // 16 K-steps
    for (int kt = 0; kt < KT; kt++) {
        const int kk = kt * 64;
        __syncthreads();   // all waves done reading previous tile's LDS
#pragma unroll
        for (int s = 0; s < 2; s++) {
            const int ko = kk + s * 32;
            gl_lds16((const char*)(gA0 + ko) + scolb, (char*)As[s] + ldsOff);
            gl_lds16((const char*)(gA1 + ko) + scolb, (char*)As[s] + ldsOff + 1024);
            gl_lds16((const char*)(gB0 + ko) + scolb, (char*)Bs[s] + ldsOff);
            gl_lds16((const char*)(gB1 + ko) + scolb, (char*)Bs[s] + ldsOff + 1024);
        }
        __syncthreads();   // compiler emits s_waitcnt vmcnt(0) drain before s_barrier

        short8 af[4][2], bf[4][2];
#pragma unroll
        for (int s = 0; s < 2; s++) {
#pragma unroll
            for (int mt = 0; mt < 4; mt++)
                af[mt][s] = *(const short8*)&As[s][(wr * 64 + mt * 16 + l15) * 32 + koffq];
#pragma unroll
            for (int nt = 0; nt < 4; nt++)
                bf[nt][s] = *(const short8*)&Bs[s][(wc * 64 + nt * 16 + l15) * 32 + koffq];
        }
#pragma unroll
        for (int s = 0; s < 2; s++)
#pragma unroll
            for (int mt = 0; mt < 4; mt++)
#pragma unroll
                for (int nt = 0; nt < 4; nt++)
                    acc[mt][nt] = mfma_bf16(af[mt][s], bf[nt][s], acc[mt][nt]);
    }

    // ---- epilogue. C layout: col = l15, row = quad*4 + reg ----
    const int proj_blk = (MODE == 0) ? (nbase >> 10) : 2;   // block-uniform: 0=Q 1=K 2=V

    const float* sB[4];
    const float* cB[4];
    if (MODE == 0 && proj_blk < 2) {
#pragma unroll
        for (int nt = 0; nt < 4; nt++) {
            const int fi = nt * 8 + (l15 >> 1);
            sB[nt] = ropeS + fi * 2048;
            cB[nt] = ropeC + fi * 2048;
        }
    }
    const int par = l15 & 1;   // 0: even d (e-slot), 1: odd d (o-slot)

#pragma unroll
    for (int mt = 0; mt < 4; mt++) {
#pragma unroll
        for (int nt = 0; nt < 4; nt++) {
            const int n  = nbase + wc * 64 + nt * 16 + l15;
            const int mb = mbase + wr * 64 + mt * 16 + quad * 4;
            f32x4 v = acc[mt][nt];
            if (MODE == 0) {
                const int e = n & 1023;
                const int h = e >> 6, d = e & 63;
                if (proj_blk == 2) {
                    const int b_ = mb >> 11, s = mb & 2047;
                    const int bh = b_ * NHEAD + h;
                    uint2 pk;                           // fp16 V (RTZ)
                    pk.x = pk_f16(v[0], v[1]);
                    pk.y = pk_f16(v[2], v[3]);
                    *(uint2*)&oVt[((size_t)bh * DK + d) * S_LEN + s] = pk;
                } else {
                    u16* dst = (proj_blk == 0) ? oQ : oK;
                    // partner values (d^1 lives in lane^1)
                    float vp[4];
#pragma unroll
                    for (int r = 0; r < 4; r++) vp[r] = __shfl_xor(v[r], 1);
                    const int b_ = mb >> 11, s0 = mb & 2047;
                    const int bh = b_ * NHEAD + h;
                    const f32x4 sn = *(const f32x4*)(sB[nt] + s0);   // s0 % 4 == 0
                    const f32x4 cs = *(const f32x4*)(cB[nt] + s0);
#pragma unroll
                    for (int r = 0; r < 4; r++) {
                        const float res = par ? (vp[r] * sn[r] + v[r] * cs[r])
                                              : (v[r] * cs[r] - vp[r] * sn[r]);
                        dst[((size_t)bh * S_LEN + (s0 + r)) * DK + d] = f2bf(res);
                    }
                }
            } else {
#pragma unroll
                for (int r = 0; r < 4; r++)
                    oF[(size_t)(mb + r) * DM + n] = v[r];
            }
        }
    }
}

// ---------- causal flash attention ----------
// R8 changes (softmax chain only — the VALU/TRANS-dominated block):
// 1. T13 defer-max: skip the rescale block (2 exp2 + 8 shfl + 48 mults) when
//    __all((mx - m_st)*SCL <= 8) — wave-uniform branch. P then bounded by 2^8;
//    f32 lacc/oacc have ~2^19 headroom over 32 tiles; final 1/lacc normalizes.
//    First-iter (-inf) takes the rescale path exactly as before.
// 2. SCL fold: scores kept RAW (max/mask monotone-invariant); P = exp2(fma(sc,
//    SCL, -m*SCL)) — deletes 32 v_mul per iter; alpha = exp2((m_old-m_new)*SCL).
// Kept: K/V frag dedup (R6), T1 XCD remap, T5 setprio, raw-barrier dist-1 dbuf.
__global__ __launch_bounds__(256)
void flash_attn(const u16* __restrict__ Q, const u16* __restrict__ K,
                const u16* __restrict__ Vt, u16* __restrict__ Oc) {
    __shared__ u16 Ks[2][64 * 64];     // permuted k-rows, XOR chunk swizzle
    __shared__ u16 Vs[2][64 * 64];     // [d][s], XOR chunk swizzle
    const int lin = (int)blockIdx.x + 64 * (int)blockIdx.y;   // [0,1024)
    const int xcd = lin & 7, idx = lin >> 3;                  // idx in [0,128)
    const int bh  = xcd * 8 + (idx & 7);
    const int qt  = 15 - (idx >> 3);
    const int tid  = threadIdx.x;
    const int wave = tid >> 6, lane = tid & 63;
    const int quad = lane >> 4, l15 = lane & 15;
    const int x7 = l15 & 7;
    const size_t headQK = (size_t)bh * S_LEN * DK;
    const size_t headVt = (size_t)bh * DK * S_LEN;
    const int b = bh >> 4, h = bh & 15;
    const float SCL = 0.18033688011112042f;   // (1/8) * log2(e)
    const float THRESH = 44.3614195558365f;   // 8 / SCL (defer-max, log2 bound 8)

    half8 ones;
#pragma unroll
    for (int j = 0; j < 8; j++) ones[j] = (_Float16)1.0f;

    const int rwl  = lane >> 3;                 // row within 8-row slab
    const int scol = (lane & 7) ^ rwl;          // XOR-swizzled chunk column
    const int rc0 = wave * 16 + rwl, rc1 = rc0 + 8;
    const u16* gK0 = K  + headQK + (size_t)perm_inv(rc0) * DK + scol * 8;
    const u16* gK1 = K  + headQK + (size_t)perm_inv(rc1) * DK + scol * 8;
    const u16* gV0 = Vt + headVt + (size_t)rc0 * S_LEN + scol * 8;
    const u16* gV1 = Vt + headVt + (size_t)rc1 * S_LEN + scol * 8;
    const int ldsOff = wave * 2048 + lane * 16;
    const int koff0 = (quad ^ x7) * 8;          // dk chunk 0..31, swizzled
    const int koff1 = ((4 + quad) ^ x7) * 8;    // dk chunk 32..63

    short8 qf[2][2];
#pragma unroll
    for (int hh = 0; hh < 2; hh++) {
        const int qrow = qt * 128 + hh * 64 + wave * 16 + l15;
        qf[hh][0] = *(const short8*)&Q[headQK + (size_t)qrow * DK + quad * 8];
        qf[hh][1] = *(const short8*)&Q[headQK + (size_t)qrow * DK + 32 + quad * 8];
    }

    float m_st[2];
    f32x4 lacc[2];
    f32x4 oacc[2][4];
#pragma unroll
    for (int hh = 0; hh < 2; hh++) {
        m_st[hh] = -__builtin_inff();
        lacc[hh] = (f32x4)0.0f;
#pragma unroll
        for (int n = 0; n < 4; n++) oacc[hh][n] = (f32x4)0.0f;
    }

    const int NT = 2 * qt + 2;
    gl_lds16(gK0, (char*)Ks[0] + ldsOff);
    gl_lds16(gK1, (char*)Ks[0] + ldsOff + 1024);
    gl_lds16(gV0, (char*)Vs[0] + ldsOff);
    gl_lds16(gV1, (char*)Vs[0] + ldsOff + 1024);

    for (int kt = 0; kt < NT; kt++) {
        const int cur = kt & 1, nxt = cur ^ 1;
        bar_raw();   // (A) everyone done reading buf[nxt]
        {            // prefetch tile kt+1 (clamped dummy on last iter)
            const int ktn = (kt + 1 < NT) ? kt + 1 : kt;
            gl_lds16(gK0 + (size_t)ktn * 64 * DK, (char*)Ks[nxt] + ldsOff);
            gl_lds16(gK1 + (size_t)ktn * 64 * DK, (char*)Ks[nxt] + ldsOff + 1024);
            gl_lds16(gV0 + ktn * 64,              (char*)Vs[nxt] + ldsOff);
            gl_lds16(gV1 + ktn * 64,              (char*)Vs[nxt] + ldsOff + 1024);
        }
        wait_vm4();  // tile kt landed; prefetch stays in flight
        bar_raw();   // (B) all waves' tile-kt staging visible

        const bool act0 = (kt != 2 * qt + 1);   // half 0 fully masked at kt==2qt+1

        // ---- QK^T, both halves, K-frags read once; scores RAW (SCL folded later) ----
        f32x4 sc[2][4];
        __builtin_amdgcn_s_setprio(1);
#pragma unroll
        for (int nt = 0; nt < 4; nt++) {
            const int rb = (nt * 16 + l15) * 64;
            short8 kf0 = *(const short8*)&Ks[cur][rb + koff0];
            short8 kf1 = *(const short8*)&Ks[cur][rb + koff1];
            f32x4 z0 = (f32x4)0.0f, z1 = (f32x4)0.0f;
            z0 = mfma_bf16(kf0, qf[0][0], z0);
            z0 = mfma_bf16(kf1, qf[0][1], z0);
            z1 = mfma_bf16(kf0, qf[1][0], z1);
            z1 = mfma_bf16(kf1, qf[1][1], z1);
            sc[0][nt] = z0;
            sc[1][nt] = z1;
        }
        __builtin_amdgcn_s_setprio(0);

        // ---- softmax per half ----
        half8 pf[2][2];
#pragma unroll
        for (int hh = 0; hh < 2; hh++) {
            if (hh == 0 && !act0) continue;
            if (kt == 2 * qt + hh) {   // diagonal tile: local k' > wave*16 + l15
                const int qloc = wave * 16 + l15;
#pragma unroll
                for (int nt = 0; nt < 4; nt++) {
                    const int kb = 32 * (nt >> 1) + 8 * quad + 4 * (nt & 1);
#pragma unroll
                    for (int r = 0; r < 4; r++)
                        if (kb + r > qloc) sc[hh][nt][r] = -__builtin_inff();
                }
            }
            float mx0 = fmaxf(fmaxf(sc[hh][0][0], sc[hh][0][1]), fmaxf(sc[hh][0][2], sc[hh][0][3]));
            float mx1 = fmaxf(fmaxf(sc[hh][1][0], sc[hh][1][1]), fmaxf(sc[hh][1][2], sc[hh][1][3]));
            float mx2 = fmaxf(fmaxf(sc[hh][2][0], sc[hh][2][1]), fmaxf(sc[hh][2][2], sc[hh][2][3]));
            float mx3 = fmaxf(fmaxf(sc[hh][3][0], sc[hh][3][1]), fmaxf(sc[hh][3][2], sc[hh][3][3]));
            float mx = fmaxf(fmaxf(mx0, mx1), fmaxf(mx2, mx3));
            mx = fmaxf(mx, __shfl_xor(mx, 16));
            mx = fmaxf(mx, __shfl_xor(mx, 32));
            // T13 defer-max: rescale only when some row's max grew past THRESH
            if (!__all(mx - m_st[hh] <= THRESH)) {
                const float mn = fmaxf(m_st[hh], mx);
                const float alpha = __builtin_amdgcn_exp2f((m_st[hh] - mn) * SCL);
                m_st[hh] = mn;
                float alr[4];
#pragma unroll
                for (int r = 0; r < 4; r++) alr[r] = __shfl(alpha, quad * 20 + r);
#pragma unroll
                for (int n = 0; n < 4; n++)
#pragma unroll
                    for (int r = 0; r < 4; r++) oacc[hh][n][r] *= alr[r];
#pragma unroll
                for (int r = 0; r < 4; r++) lacc[hh][r] *= alr[r];
            }
            // P = exp2(fma(sc, SCL, -m*SCL)); bounded by 2^8 when deferred
            const float msc = m_st[hh] * SCL;
#pragma unroll
            for (int nt = 0; nt < 4; nt++)
#pragma unroll
                for (int r = 0; r < 4; r++)
                    sc[hh][nt][r] = __builtin_amdgcn_exp2f(
                        __builtin_fmaf(sc[hh][nt][r], SCL, -msc));
            u32 pw[8];
            pw[0] = pk_f16(sc[hh][0][0], sc[hh][0][1]); pw[1] = pk_f16(sc[hh][0][2], sc[hh][0][3]);
            pw[2] = pk_f16(sc[hh][1][0], sc[hh][1][1]); pw[3] = pk_f16(sc[hh][1][2], sc[hh][1][3]);
            pw[4] = pk_f16(sc[hh][2][0], sc[hh][2][1]); pw[5] = pk_f16(sc[hh][2][2], sc[hh][2][3]);
            pw[6] = pk_f16(sc[hh][3][0], sc[hh][3][1]); pw[7] = pk_f16(sc[hh][3][2], sc[hh][3][3]);
            pf[hh][0] = __builtin_bit_cast(half8, *(uint4*)&pw[0]);
            pf[hh][1] = __builtin_bit_cast(half8, *(uint4*)&pw[4]);
        }

        // ---- PV + row-sum, both halves, V-frags read once ----
        __builtin_amdgcn_s_setprio(1);
#pragma unroll
        for (int c = 0; c < 2; c++) {
            if (act0) lacc[0] = mfma_f16(pf[0][c], ones, lacc[0]);
            lacc[1] = mfma_f16(pf[1][c], ones, lacc[1]);
            const int voff = ((c * 4 + quad) ^ x7) * 8;
#pragma unroll
            for (int nt2 = 0; nt2 < 4; nt2++) {
                half8 vf = __builtin_bit_cast(half8,
                    *(const short8*)&Vs[cur][(nt2 * 16 + l15) * 64 + voff]);
                if (act0) oacc[0][nt2] = mfma_f16(pf[0][c], vf, oacc[0][nt2]);
                oacc[1][nt2] = mfma_f16(pf[1][c], vf, oacc[1][nt2]);
            }
        }
        __builtin_amdgcn_s_setprio(0);
    }
    wait_vm0();   // drain dangling dummy prefetch before exit

#pragma unroll
    for (int hh = 0; hh < 2; hh++) {
#pragma unroll
        for (int r = 0; r < 4; r++) {
            const float inv = 1.0f / lacc[hh][r];
            const int s = qt * 128 + hh * 64 + wave * 16 + quad * 4 + r;
#pragma unroll
            for (int nt2 = 0; nt2 < 4; nt2++)
                Oc[((size_t)(b * S_LEN + s)) * DM + h * 64 + nt2 * 16 + l15] =
                    f2bf(oacc[hh][nt2][r] * inv);
        }
    }
}

// ---------- workspace layout (u16 elements) ----------
#define OFF_XBF   ((size_t)0)
#define OFF_WCAT  ((size_t)8388608)
#define OFF_WO    ((size_t)11534336)
#define OFF_QB    ((size_t)12582912)
#define OFF_KB    ((size_t)20971520)
#define OFF_VT    ((size_t)29360128)
#define OFF_ROPE  ((size_t)37748736)   // 65536 fp32 sin + 65536 fp32 cos = 512 KB

extern "C" void kernel_launch(void* const* d_in, const int* in_sizes, int n_in,
                              void* d_out, int out_size, void* d_ws, size_t ws_size,
                              hipStream_t stream) {
    const float* x  = (const float*)d_in[0];
    const float* Wq = (const float*)d_in[1];
    const float* Wk = (const float*)d_in[2];
    const float* Wv = (const float*)d_in[3];
    const float* Wo = (const float*)d_in[4];
    u16* ws  = (u16*)d_ws;
    u16* XBF = ws + OFF_XBF;
    u16* WCA = ws + OFF_WCAT;
    u16* WOB = ws + OFF_WO;
    u16* QB  = ws + OFF_QB;
    u16* KB  = ws + OFF_KB;
    u16* VT  = ws + OFF_VT;
    float* ropeS = (float*)(ws + OFF_ROPE);
    float* ropeC = ropeS + 65536;
    u16* AT  = XBF;   // reuse

    cvt_all<<<12544, 256, 0, stream>>>((const float4*)x, (const float4*)Wq,
                                       (const float4*)Wk, (const float4*)Wv,
                                       (const float4*)Wo,
                                       (uint2*)XBF, (uint2*)WCA, (uint2*)WOB,
                                       ropeS, ropeC);

    gemm_nt<0><<<dim3(24, 64), 256, 0, stream>>>(XBF, WCA, QB, KB, VT, nullptr,
                                                 ropeS, ropeC);
    flash_attn<<<dim3(64, 16), 256, 0, stream>>>(QB, KB, VT, AT);
    gemm_nt<1><<<dim3(8, 64), 256, 0, stream>>>(AT, WOB, nullptr, nullptr, nullptr,
                                                (float*)d_out, nullptr, nullptr);
}

// Round 12
// 256.952 us; speedup vs baseline: 1.1422x; 1.0270x over previous
//
#include <hip/hip_runtime.h>

typedef unsigned short u16;
typedef unsigned int   u32;

typedef short    short8 __attribute__((ext_vector_type(8)));
typedef __bf16   bf16x8 __attribute__((ext_vector_type(8)));
typedef _Float16 half8  __attribute__((ext_vector_type(8)));
typedef float    f32x4  __attribute__((ext_vector_type(4)));

#define S_LEN   2048
#define DM      1024
#define NHEAD   16
#define DK      64
#define KDIM    1024

// ---------- helpers ----------
__device__ __forceinline__ u16 f2bf(float f) {
    u32 u = __builtin_bit_cast(u32, f);
    u += 0x7FFFu + ((u >> 16) & 1u);      // RNE
    return (u16)(u >> 16);
}
__device__ __forceinline__ f32x4 mfma_bf16(short8 a, short8 b, f32x4 c) {
    return __builtin_amdgcn_mfma_f32_16x16x32_bf16(
        __builtin_bit_cast(bf16x8, a), __builtin_bit_cast(bf16x8, b), c, 0, 0, 0);
}
__device__ __forceinline__ f32x4 mfma_f16(half8 a, half8 b, f32x4 c) {
    return __builtin_amdgcn_mfma_f32_16x16x32_f16(a, b, c, 0, 0, 0);
}
__device__ __forceinline__ u32 pk_f16(float a, float b) {
    return __builtin_bit_cast(u32, __builtin_amdgcn_cvt_pkrtz(a, b));
}
__device__ __forceinline__ void gl_lds16(const void* g, void* l) {
    __builtin_amdgcn_global_load_lds(
        (const __attribute__((address_space(1))) u32*)g,
        (__attribute__((address_space(3))) u32*)l, 16, 0, 0);
}
// raw barrier / waitcnt (flash only): prefetch stays in flight across barrier
__device__ __forceinline__ void bar_raw() { asm volatile("s_barrier" ::: "memory"); }
__device__ __forceinline__ void wait_vm4() { asm volatile("s_waitcnt vmcnt(4)" ::: "memory"); }
__device__ __forceinline__ void wait_vm0() { asm volatile("s_waitcnt vmcnt(0)" ::: "memory"); }

// K-row permutation for flash: LDS row rc holds global k-row perm_inv(rc) so that
// PV A-frags are in-lane after S^T: k'(nt,quad,r)=32*(nt>>1)+8*quad+4*(nt&1)+r
__device__ __forceinline__ int perm_inv(int rc) {
    const int nt = rc >> 4, mid = (rc >> 2) & 3, r = rc & 3;
    return 32 * (nt >> 1) + 8 * mid + 4 * (nt & 1) + r;
}

// ---------- fused fp32->bf16 convert + RoPE table build ----------
__global__ void cvt_all(const float4* __restrict__ x,  const float4* __restrict__ Wq,
                        const float4* __restrict__ Wk, const float4* __restrict__ Wv,
                        const float4* __restrict__ Wo,
                        uint2* __restrict__ oX, uint2* __restrict__ oWcat,
                        uint2* __restrict__ oWo,
                        float* __restrict__ sT, float* __restrict__ cT) {
    const int i = blockIdx.x * 256 + threadIdx.x;
    if (i < 3145728) {
        const float4* in;
        uint2* out;
        if (i < 2097152) {
            in = x + i;  out = oX + i;
        } else {
            const int j = i - 2097152;
            const int w = j >> 18, k = j & 262143;
            in  = (w == 0 ? Wq : w == 1 ? Wk : w == 2 ? Wv : Wo) + k;
            out = (w < 3) ? (oWcat + w * 262144 + k) : (oWo + k);
        }
        float4 f = *in;
        uint2 o;
        o.x = (u32)f2bf(f.x) | ((u32)f2bf(f.y) << 16);
        o.y = (u32)f2bf(f.z) | ((u32)f2bf(f.w) << 16);
        *out = o;
    } else {
        const int idx = i - 3145728;            // [0, 65536): i=idx>>11, s=idx&2047
        const float fi = expf(-(float)(idx >> 11) * 0.287823136624255f);
        const float ang = (float)(idx & 2047) * fi;
        sT[idx] = sinf(ang);
        cT[idx] = cosf(ang);
    }
}

// ---------- NT GEMM, m97-exact structure (banked 89.1us): BM=BN=128, BK=64 ----------
// Single-buffered 32KB LDS, __syncthreads pair (compiler emits vmcnt(0) drain),
// 32 MFMA per barrier-pair, cross-block TLP provides the overlap (m114).
// BK=64 as TWO 32-col sub-tiles, each with R2's conflict-free XOR chunk swizzle.
// K=1024 shape pins the 128^2 family at ~570 TF — GEMM lever exhausted (R2-R8).
// T1 XCD remap kept. MODE 0: QKV+RoPE epilogue; MODE 1: fp32 store.
template <int MODE>
__global__ __launch_bounds__(256)
void gemm_nt(const u16* __restrict__ A, const u16* __restrict__ Bw,
             u16* __restrict__ oQ, u16* __restrict__ oK, u16* __restrict__ oVt,
             float* __restrict__ oF,
             const float* __restrict__ ropeS, const float* __restrict__ ropeC) {
    __shared__ u16 As[2][128 * 32];   // [k-slice][128 rows x 32 cols], single-buffered
    __shared__ u16 Bs[2][128 * 32];
    const int tid  = threadIdx.x;
    const int wave = tid >> 6, lane = tid & 63;
    const int quad = lane >> 4, l15 = lane & 15;
    const int wr = wave >> 1, wc = wave & 1;
    // T1 remap: lin -> (xcd, idx); y = xcd*8 + idx/NX, x = idx%NX
    const int NX  = (MODE == 0) ? 24 : 8;
    const int lin = (int)blockIdx.x + NX * (int)blockIdx.y;
    const int xcd = lin & 7, idx = lin >> 3;
    const int mbase = (xcd * 8 + idx / NX) * 128;
    const int nbase = (idx % NX) * 128;

    f32x4 acc[4][4];
#pragma unroll
    for (int i = 0; i < 4; i++)
#pragma unroll
        for (int j = 0; j < 4; j++) acc[i][j] = (f32x4)0.0f;

    // staging (per 32-col sub-tile, R2-proven): physical chunk (lane&3) of row srow
    // holds global chunk (lane&3)^((srow>>1)&3); 2 row-blocks (srow, srow+16)/call pair
    const int srow0 = wave * 32 + (lane >> 2);
    const int srow1 = srow0 + 16;
    const int scolb = ((lane & 3) ^ ((lane >> 3) & 3)) * 16;   // bytes within 64B subrow
    const int ldsOff = wave * 2048 + lane * 16;                // bytes
    const u16* gA0 = A  + (size_t)(mbase + srow0) * KDIM;
    const u16* gA1 = A  + (size_t)(mbase + srow1) * KDIM;
    const u16* gB0 = Bw + (size_t)(nbase + srow0) * KDIM;
    const u16* gB1 = Bw + (size_t)(nbase + srow1) * KDIM;
    // fragment read: chunk quad of row R at physical chunk quad^((l15>>1)&3)
    const int koffq = (quad ^ ((l15 >> 1) & 3)) * 8;    // u16 units

    const int KT = KDIM / 64;   // 16 K-steps
    for (int kt = 0; kt < KT; kt++) {
        const int kk = kt * 64;
        __syncthreads();   // all waves done reading previous tile's LDS
#pragma unroll
        for (int s = 0; s < 2; s++) {
            const int ko = kk + s * 32;
            gl_lds16((const char*)(gA0 + ko) + scolb, (char*)As[s] + ldsOff);
            gl_lds16((const char*)(gA1 + ko) + scolb, (char*)As[s] + ldsOff + 1024);
            gl_lds16((const char*)(gB0 + ko) + scolb, (char*)Bs[s] + ldsOff);
            gl_lds16((const char*)(gB1 + ko) + scolb, (char*)Bs[s] + ldsOff + 1024);
        }
        __syncthreads();   // compiler emits s_waitcnt vmcnt(0) drain before s_barrier

        short8 af[4][2], bf[4][2];
#pragma unroll
        for (int s = 0; s < 2; s++) {
#pragma unroll
            for (int mt = 0; mt < 4; mt++)
                af[mt][s] = *(const short8*)&As[s][(wr * 64 + mt * 16 + l15) * 32 + koffq];
#pragma unroll
            for (int nt = 0; nt < 4; nt++)
                bf[nt][s] = *(const short8*)&Bs[s][(wc * 64 + nt * 16 + l15) * 32 + koffq];
        }
#pragma unroll
        for (int s = 0; s < 2; s++)
#pragma unroll
            for (int mt = 0; mt < 4; mt++)
#pragma unroll
                for (int nt = 0; nt < 4; nt++)
                    acc[mt][nt] = mfma_bf16(af[mt][s], bf[nt][s], acc[mt][nt]);
    }

    // ---- epilogue. C layout: col = l15, row = quad*4 + reg ----
    const int proj_blk = (MODE == 0) ? (nbase >> 10) : 2;   // block-uniform: 0=Q 1=K 2=V

    const float* sB[4];
    const float* cB[4];
    if (MODE == 0 && proj_blk < 2) {
#pragma unroll
        for (int nt = 0; nt < 4; nt++) {
            const int fi = nt * 8 + (l15 >> 1);
            sB[nt] = ropeS + fi * 2048;
            cB[nt] = ropeC + fi * 2048;
        }
    }
    const int par = l15 & 1;   // 0: even d (e-slot), 1: odd d (o-slot)

#pragma unroll
    for (int mt = 0; mt < 4; mt++) {
#pragma unroll
        for (int nt = 0; nt < 4; nt++) {
            const int n  = nbase + wc * 64 + nt * 16 + l15;
            const int mb = mbase + wr * 64 + mt * 16 + quad * 4;
            f32x4 v = acc[mt][nt];
            if (MODE == 0) {
                const int e = n & 1023;
                const int h = e >> 6, d = e & 63;
                if (proj_blk == 2) {
                    const int b_ = mb >> 11, s = mb & 2047;
                    const int bh = b_ * NHEAD + h;
                    uint2 pk;                           // fp16 V (RTZ)
                    pk.x = pk_f16(v[0], v[1]);
                    pk.y = pk_f16(v[2], v[3]);
                    *(uint2*)&oVt[((size_t)bh * DK + d) * S_LEN + s] = pk;
                } else {
                    u16* dst = (proj_blk == 0) ? oQ : oK;
                    // partner values (d^1 lives in lane^1)
                    float vp[4];
#pragma unroll
                    for (int r = 0; r < 4; r++) vp[r] = __shfl_xor(v[r], 1);
                    const int b_ = mb >> 11, s0 = mb & 2047;
                    const int bh = b_ * NHEAD + h;
                    const f32x4 sn = *(const f32x4*)(sB[nt] + s0);   // s0 % 4 == 0
                    const f32x4 cs = *(const f32x4*)(cB[nt] + s0);
#pragma unroll
                    for (int r = 0; r < 4; r++) {
                        const float res = par ? (vp[r] * sn[r] + v[r] * cs[r])
                                              : (v[r] * cs[r] - vp[r] * sn[r]);
                        dst[((size_t)bh * S_LEN + (s0 + r)) * DK + d] = f2bf(res);
                    }
                }
            } else {
#pragma unroll
                for (int r = 0; r < 4; r++)
                    oF[(size_t)(mb + r) * DM + n] = v[r];
            }
        }
    }
}

// ---------- causal flash attention: R9 — per-half blocks (QBLK=64) ----------
// Theory: the 128-row/2-half-per-wave structure was latency-bound — VGPR-heavy
// (two halves of sc/oacc/pf live) capping resident waves/SIMD, all 1024 blocks
// co-resident (no rebalancing), and a 2x serial softmax chain per barrier
// interval. This kernel: grid (64 heads x 32 q-half-tiles) = 2048 blocks, each
// 4 waves x ONE 16-row chain. VGPR ~halves -> more waves/SIMD; 8 blocks/CU
// demand vs 5 resident -> greedy heavy-first rebalancing; serial chain per
// barrier halves. Every (row,kt) sees identical ops in identical order ->
// bitwise-identical output. K/V staged per 64-row block (2x L2 traffic — the
// R6 dedup savings, measured neutral, spent back).
// NT = qt+1 k-tiles (64-col); diagonal at kt==qt. T13 defer-max + SCL fold (R8),
// T1 XCD remap, T5 setprio, raw-barrier dist-1 dbuf kept.
__global__ __launch_bounds__(256)
void flash_attn(const u16* __restrict__ Q, const u16* __restrict__ K,
                const u16* __restrict__ Vt, u16* __restrict__ Oc) {
    __shared__ u16 Ks[2][64 * 64];     // permuted k-rows, XOR chunk swizzle
    __shared__ u16 Vs[2][64 * 64];     // [d][s], XOR chunk swizzle
    const int lin = (int)blockIdx.x + 64 * (int)blockIdx.y;   // [0,2048)
    const int xcd = lin & 7, idx = lin >> 3;                  // idx in [0,256)
    const int bh  = xcd * 8 + (idx & 7);
    const int qt  = 31 - (idx >> 3);                          // [0,32), heavy first
    const int tid  = threadIdx.x;
    const int wave = tid >> 6, lane = tid & 63;
    const int quad = lane >> 4, l15 = lane & 15;
    const int x7 = l15 & 7;
    const size_t headQK = (size_t)bh * S_LEN * DK;
    const size_t headVt = (size_t)bh * DK * S_LEN;
    const int b = bh >> 4, h = bh & 15;
    const float SCL = 0.18033688011112042f;   // (1/8) * log2(e)
    const float THRESH = 44.3614195558365f;   // 8 / SCL (defer-max, log2 bound 8)

    half8 ones;
#pragma unroll
    for (int j = 0; j < 8; j++) ones[j] = (_Float16)1.0f;

    const int rwl  = lane >> 3;                 // row within 8-row slab
    const int scol = (lane & 7) ^ rwl;          // XOR-swizzled chunk column
    const int rc0 = wave * 16 + rwl, rc1 = rc0 + 8;
    const u16* gK0 = K  + headQK + (size_t)perm_inv(rc0) * DK + scol * 8;
    const u16* gK1 = K  + headQK + (size_t)perm_inv(rc1) * DK + scol * 8;
    const u16* gV0 = Vt + headVt + (size_t)rc0 * S_LEN + scol * 8;
    const u16* gV1 = Vt + headVt + (size_t)rc1 * S_LEN + scol * 8;
    const int ldsOff = wave * 2048 + lane * 16;
    const int koff0 = (quad ^ x7) * 8;          // dk chunk 0..31, swizzled
    const int koff1 = ((4 + quad) ^ x7) * 8;    // dk chunk 32..63

    // Q B-fragments (one 16-row group per wave)
    short8 qf0, qf1;
    {
        const int qrow = qt * 64 + wave * 16 + l15;
        qf0 = *(const short8*)&Q[headQK + (size_t)qrow * DK + quad * 8];
        qf1 = *(const short8*)&Q[headQK + (size_t)qrow * DK + 32 + quad * 8];
    }

    float m_st = -__builtin_inff();
    f32x4 lacc = (f32x4)0.0f;
    f32x4 oacc[4];
#pragma unroll
    for (int n = 0; n < 4; n++) oacc[n] = (f32x4)0.0f;

    const int NT = qt + 1;
    gl_lds16(gK0, (char*)Ks[0] + ldsOff);
    gl_lds16(gK1, (char*)Ks[0] + ldsOff + 1024);
    gl_lds16(gV0, (char*)Vs[0] + ldsOff);
    gl_lds16(gV1, (char*)Vs[0] + ldsOff + 1024);

    for (int kt = 0; kt < NT; kt++) {
        const int cur = kt & 1, nxt = cur ^ 1;
        bar_raw();   // (A) everyone done reading buf[nxt]
        {            // prefetch tile kt+1 (clamped dummy on last iter)
            const int ktn = (kt + 1 < NT) ? kt + 1 : kt;
            gl_lds16(gK0 + (size_t)ktn * 64 * DK, (char*)Ks[nxt] + ldsOff);
            gl_lds16(gK1 + (size_t)ktn * 64 * DK, (char*)Ks[nxt] + ldsOff + 1024);
            gl_lds16(gV0 + ktn * 64,              (char*)Vs[nxt] + ldsOff);
            gl_lds16(gV1 + ktn * 64,              (char*)Vs[nxt] + ldsOff + 1024);
        }
        wait_vm4();  // tile kt landed; prefetch stays in flight
        bar_raw();   // (B) all waves' tile-kt staging visible

        // ---- QK^T (scores RAW; SCL folded into exp2) ----
        f32x4 sc[4];
        __builtin_amdgcn_s_setprio(1);
#pragma unroll
        for (int nt = 0; nt < 4; nt++) {
            const int rb = (nt * 16 + l15) * 64;
            short8 kf0 = *(const short8*)&Ks[cur][rb + koff0];
            short8 kf1 = *(const short8*)&Ks[cur][rb + koff1];
            f32x4 z = (f32x4)0.0f;
            z = mfma_bf16(kf0, qf0, z);
            z = mfma_bf16(kf1, qf1, z);
            sc[nt] = z;
        }
        __builtin_amdgcn_s_setprio(0);

        if (kt == qt) {   // diagonal tile: local k' > wave*16 + l15
            const int qloc = wave * 16 + l15;
#pragma unroll
            for (int nt = 0; nt < 4; nt++) {
                const int kb = 32 * (nt >> 1) + 8 * quad + 4 * (nt & 1);
#pragma unroll
                for (int r = 0; r < 4; r++)
                    if (kb + r > qloc) sc[nt][r] = -__builtin_inff();
            }
        }
        // row max: in-lane over 16, then across quads
        float mx0 = fmaxf(fmaxf(sc[0][0], sc[0][1]), fmaxf(sc[0][2], sc[0][3]));
        float mx1 = fmaxf(fmaxf(sc[1][0], sc[1][1]), fmaxf(sc[1][2], sc[1][3]));
        float mx2 = fmaxf(fmaxf(sc[2][0], sc[2][1]), fmaxf(sc[2][2], sc[2][3]));
        float mx3 = fmaxf(fmaxf(sc[3][0], sc[3][1]), fmaxf(sc[3][2], sc[3][3]));
        float mx = fmaxf(fmaxf(mx0, mx1), fmaxf(mx2, mx3));
        mx = fmaxf(mx, __shfl_xor(mx, 16));
        mx = fmaxf(mx, __shfl_xor(mx, 32));
        // T13 defer-max: rescale only when some row's max grew past THRESH
        if (!__all(mx - m_st <= THRESH)) {
            const float mn = fmaxf(m_st, mx);
            const float alpha = __builtin_amdgcn_exp2f((m_st - mn) * SCL);
            m_st = mn;
            float alr[4];
#pragma unroll
            for (int r = 0; r < 4; r++) alr[r] = __shfl(alpha, quad * 20 + r);
#pragma unroll
            for (int n = 0; n < 4; n++)
#pragma unroll
                for (int r = 0; r < 4; r++) oacc[n][r] *= alr[r];
#pragma unroll
            for (int r = 0; r < 4; r++) lacc[r] *= alr[r];
        }
        // P = exp2(fma(sc, SCL, -m*SCL)); bounded by 2^8 when deferred
        const float msc = m_st * SCL;
#pragma unroll
        for (int nt = 0; nt < 4; nt++)
#pragma unroll
            for (int r = 0; r < 4; r++)
                sc[nt][r] = __builtin_amdgcn_exp2f(
                    __builtin_fmaf(sc[nt][r], SCL, -msc));
        u32 pw[8];
        pw[0] = pk_f16(sc[0][0], sc[0][1]); pw[1] = pk_f16(sc[0][2], sc[0][3]);
        pw[2] = pk_f16(sc[1][0], sc[1][1]); pw[3] = pk_f16(sc[1][2], sc[1][3]);
        pw[4] = pk_f16(sc[2][0], sc[2][1]); pw[5] = pk_f16(sc[2][2], sc[2][3]);
        pw[6] = pk_f16(sc[3][0], sc[3][1]); pw[7] = pk_f16(sc[3][2], sc[3][3]);
        half8 pf0 = __builtin_bit_cast(half8, *(uint4*)&pw[0]);
        half8 pf1 = __builtin_bit_cast(half8, *(uint4*)&pw[4]);

        // ---- PV + row-sum (fp16) ----
        __builtin_amdgcn_s_setprio(1);
#pragma unroll
        for (int c = 0; c < 2; c++) {
            const half8 pf = c ? pf1 : pf0;
            lacc = mfma_f16(pf, ones, lacc);
            const int voff = ((c * 4 + quad) ^ x7) * 8;
#pragma unroll
            for (int nt2 = 0; nt2 < 4; nt2++) {
                half8 vf = __builtin_bit_cast(half8,
                    *(const short8*)&Vs[cur][(nt2 * 16 + l15) * 64 + voff]);
                oacc[nt2] = mfma_f16(pf, vf, oacc[nt2]);
            }
        }
        __builtin_amdgcn_s_setprio(0);
    }
    wait_vm0();   // drain dangling dummy prefetch before exit

    // epilogue: rows quad*4+r, cols l15
#pragma unroll
    for (int r = 0; r < 4; r++) {
        const float inv = 1.0f / lacc[r];
        const int s = qt * 64 + wave * 16 + quad * 4 + r;
#pragma unroll
        for (int nt2 = 0; nt2 < 4; nt2++)
            Oc[((size_t)(b * S_LEN + s)) * DM + h * 64 + nt2 * 16 + l15] =
                f2bf(oacc[nt2][r] * inv);
    }
}

// ---------- workspace layout (u16 elements) ----------
#define OFF_XBF   ((size_t)0)
#define OFF_WCAT  ((size_t)8388608)
#define OFF_WO    ((size_t)11534336)
#define OFF_QB    ((size_t)12582912)
#define OFF_KB    ((size_t)20971520)
#define OFF_VT    ((size_t)29360128)
#define OFF_ROPE  ((size_t)37748736)   // 65536 fp32 sin + 65536 fp32 cos = 512 KB

extern "C" void kernel_launch(void* const* d_in, const int* in_sizes, int n_in,
                              void* d_out, int out_size, void* d_ws, size_t ws_size,
                              hipStream_t stream) {
    const float* x  = (const float*)d_in[0];
    const float* Wq = (const float*)d_in[1];
    const float* Wk = (const float*)d_in[2];
    const float* Wv = (const float*)d_in[3];
    const float* Wo = (const float*)d_in[4];
    u16* ws  = (u16*)d_ws;
    u16* XBF = ws + OFF_XBF;
    u16* WCA = ws + OFF_WCAT;
    u16* WOB = ws + OFF_WO;
    u16* QB  = ws + OFF_QB;
    u16* KB  = ws + OFF_KB;
    u16* VT  = ws + OFF_VT;
    float* ropeS = (float*)(ws + OFF_ROPE);
    float* ropeC = ropeS + 65536;
    u16* AT  = XBF;   // reuse

    cvt_all<<<12544, 256, 0, stream>>>((const float4*)x, (const float4*)Wq,
                                       (const float4*)Wk, (const float4*)Wv,
                                       (const float4*)Wo,
                                       (uint2*)XBF, (uint2*)WCA, (uint2*)WOB,
                                       ropeS, ropeC);

    gemm_nt<0><<<dim3(24, 64), 256, 0, stream>>>(XBF, WCA, QB, KB, VT, nullptr,
                                                 ropeS, ropeC);
    flash_attn<<<dim3(64, 32), 256, 0, stream>>>(QB, KB, VT, AT);
    gemm_nt<1><<<dim3(8, 64), 256, 0, stream>>>(AT, WOB, nullptr, nullptr, nullptr,
                                                (float*)d_out, nullptr, nullptr);
}

// Round 13
// 245.782 us; speedup vs baseline: 1.1942x; 1.0454x over previous
//
#include <hip/hip_runtime.h>

typedef unsigned short u16;
typedef unsigned int   u32;

typedef short    short8 __attribute__((ext_vector_type(8)));
typedef __bf16   bf16x8 __attribute__((ext_vector_type(8)));
typedef _Float16 half8  __attribute__((ext_vector_type(8)));
typedef float    f32x4  __attribute__((ext_vector_type(4)));

#define S_LEN   2048
#define DM      1024
#define NHEAD   16
#define DK      64
#define KDIM    1024

// ---------- helpers ----------
__device__ __forceinline__ u16 f2bf(float f) {
    u32 u = __builtin_bit_cast(u32, f);
    u += 0x7FFFu + ((u >> 16) & 1u);      // RNE
    return (u16)(u >> 16);
}
__device__ __forceinline__ f32x4 mfma_bf16(short8 a, short8 b, f32x4 c) {
    return __builtin_amdgcn_mfma_f32_16x16x32_bf16(
        __builtin_bit_cast(bf16x8, a), __builtin_bit_cast(bf16x8, b), c, 0, 0, 0);
}
__device__ __forceinline__ f32x4 mfma_f16(half8 a, half8 b, f32x4 c) {
    return __builtin_amdgcn_mfma_f32_16x16x32_f16(a, b, c, 0, 0, 0);
}
__device__ __forceinline__ u32 pk_f16(float a, float b) {
    return __builtin_bit_cast(u32, __builtin_amdgcn_cvt_pkrtz(a, b));
}
__device__ __forceinline__ void gl_lds16(const void* g, void* l) {
    __builtin_amdgcn_global_load_lds(
        (const __attribute__((address_space(1))) u32*)g,
        (__attribute__((address_space(3))) u32*)l, 16, 0, 0);
}
// raw barrier / waitcnt (flash only): prefetch stays in flight across barrier
__device__ __forceinline__ void bar_raw() { asm volatile("s_barrier" ::: "memory"); }
__device__ __forceinline__ void wait_vm2() { asm volatile("s_waitcnt vmcnt(2)" ::: "memory"); }
__device__ __forceinline__ void wait_vm0() { asm volatile("s_waitcnt vmcnt(0)" ::: "memory"); }

// K-row permutation for flash: LDS row rc holds global k-row perm_inv(rc) so that
// PV A-frags are in-lane after S^T: k'(nt,quad,r)=32*(nt>>1)+8*quad+4*(nt&1)+r
__device__ __forceinline__ int perm_inv(int rc) {
    const int nt = rc >> 4, mid = (rc >> 2) & 3, r = rc & 3;
    return 32 * (nt >> 1) + 8 * mid + 4 * (nt & 1) + r;
}

// ---------- fused fp32->bf16 convert + RoPE table build ----------
__global__ void cvt_all(const float4* __restrict__ x,  const float4* __restrict__ Wq,
                        const float4* __restrict__ Wk, const float4* __restrict__ Wv,
                        const float4* __restrict__ Wo,
                        uint2* __restrict__ oX, uint2* __restrict__ oWcat,
                        uint2* __restrict__ oWo,
                        float* __restrict__ sT, float* __restrict__ cT) {
    const int i = blockIdx.x * 256 + threadIdx.x;
    if (i < 3145728) {
        const float4* in;
        uint2* out;
        if (i < 2097152) {
            in = x + i;  out = oX + i;
        } else {
            const int j = i - 2097152;
            const int w = j >> 18, k = j & 262143;
            in  = (w == 0 ? Wq : w == 1 ? Wk : w == 2 ? Wv : Wo) + k;
            out = (w < 3) ? (oWcat + w * 262144 + k) : (oWo + k);
        }
        float4 f = *in;
        uint2 o;
        o.x = (u32)f2bf(f.x) | ((u32)f2bf(f.y) << 16);
        o.y = (u32)f2bf(f.z) | ((u32)f2bf(f.w) << 16);
        *out = o;
    } else {
        const int idx = i - 3145728;            // [0, 65536): i=idx>>11, s=idx&2047
        const float fi = expf(-(float)(idx >> 11) * 0.287823136624255f);
        const float ang = (float)(idx & 2047) * fi;
        sT[idx] = sinf(ang);
        cT[idx] = cosf(ang);
    }
}

// ---------- NT GEMM, m97-exact structure (banked 89.1us): BM=BN=128, BK=64 ----------
// Single-buffered 32KB LDS, __syncthreads pair (compiler emits vmcnt(0) drain),
// 32 MFMA per barrier-pair, cross-block TLP provides the overlap (m114).
// BK=64 as TWO 32-col sub-tiles, each with R2's conflict-free XOR chunk swizzle.
// K=1024 shape pins the 128^2 family at ~570 TF — GEMM lever exhausted (R2-R8).
// T1 XCD remap kept. MODE 0: QKV+RoPE epilogue; MODE 1: fp32 store.
template <int MODE>
__global__ __launch_bounds__(256)
void gemm_nt(const u16* __restrict__ A, const u16* __restrict__ Bw,
             u16* __restrict__ oQ, u16* __restrict__ oK, u16* __restrict__ oVt,
             float* __restrict__ oF,
             const float* __restrict__ ropeS, const float* __restrict__ ropeC) {
    __shared__ u16 As[2][128 * 32];   // [k-slice][128 rows x 32 cols], single-buffered
    __shared__ u16 Bs[2][128 * 32];
    const int tid  = threadIdx.x;
    const int wave = tid >> 6, lane = tid & 63;
    const int quad = lane >> 4, l15 = lane & 15;
    const int wr = wave >> 1, wc = wave & 1;
    // T1 remap: lin -> (xcd, idx); y = xcd*8 + idx/NX, x = idx%NX
    const int NX  = (MODE == 0) ? 24 : 8;
    const int lin = (int)blockIdx.x + NX * (int)blockIdx.y;
    const int xcd = lin & 7, idx = lin >> 3;
    const int mbase = (xcd * 8 + idx / NX) * 128;
    const int nbase = (idx % NX) * 128;

    f32x4 acc[4][4];
#pragma unroll
    for (int i = 0; i < 4; i++)
#pragma unroll
        for (int j = 0; j < 4; j++) acc[i][j] = (f32x4)0.0f;

    // staging (per 32-col sub-tile, R2-proven): physical chunk (lane&3) of row srow
    // holds global chunk (lane&3)^((srow>>1)&3); 2 row-blocks (srow, srow+16)/call pair
    const int srow0 = wave * 32 + (lane >> 2);
    const int srow1 = srow0 + 16;
    const int scolb = ((lane & 3) ^ ((lane >> 3) & 3)) * 16;   // bytes within 64B subrow
    const int ldsOff = wave * 2048 + lane * 16;                // bytes
    const u16* gA0 = A  + (size_t)(mbase + srow0) * KDIM;
    const u16* gA1 = A  + (size_t)(mbase + srow1) * KDIM;
    const u16* gB0 = Bw + (size_t)(nbase + srow0) * KDIM;
    const u16* gB1 = Bw + (size_t)(nbase + srow1) * KDIM;
    // fragment read: chunk quad of row R at physical chunk quad^((l15>>1)&3)
    const int koffq = (quad ^ ((l15 >> 1) & 3)) * 8;    // u16 units

    const int KT = KDIM / 64;   // 16 K-steps
    for (int kt = 0; kt < KT; kt++) {
        const int kk = kt * 64;
        __syncthreads();   // all waves done reading previous tile's LDS
#pragma unroll
        for (int s = 0; s < 2; s++) {
            const int ko = kk + s * 32;
            gl_lds16((const char*)(gA0 + ko) + scolb, (char*)As[s] + ldsOff);
            gl_lds16((const char*)(gA1 + ko) + scolb, (char*)As[s] + ldsOff + 1024);
            gl_lds16((const char*)(gB0 + ko) + scolb, (char*)Bs[s] + ldsOff);
            gl_lds16((const char*)(gB1 + ko) + scolb, (char*)Bs[s] + ldsOff + 1024);
        }
        __syncthreads();   // compiler emits s_waitcnt vmcnt(0) drain before s_barrier

        short8 af[4][2], bf[4][2];
#pragma unroll
        for (int s = 0; s < 2; s++) {
#pragma unroll
            for (int mt = 0; mt < 4; mt++)
                af[mt][s] = *(const short8*)&As[s][(wr * 64 + mt * 16 + l15) * 32 + koffq];
#pragma unroll
            for (int nt = 0; nt < 4; nt++)
                bf[nt][s] = *(const short8*)&Bs[s][(wc * 64 + nt * 16 + l15) * 32 + koffq];
        }
#pragma unroll
        for (int s = 0; s < 2; s++)
#pragma unroll
            for (int mt = 0; mt < 4; mt++)
#pragma unroll
                for (int nt = 0; nt < 4; nt++)
                    acc[mt][nt] = mfma_bf16(af[mt][s], bf[nt][s], acc[mt][nt]);
    }

    // ---- epilogue. C layout: col = l15, row = quad*4 + reg ----
    const int proj_blk = (MODE == 0) ? (nbase >> 10) : 2;   // block-uniform: 0=Q 1=K 2=V

    const float* sB[4];
    const float* cB[4];
    if (MODE == 0 && proj_blk < 2) {
#pragma unroll
        for (int nt = 0; nt < 4; nt++) {
            const int fi = nt * 8 + (l15 >> 1);
            sB[nt] = ropeS + fi * 2048;
            cB[nt] = ropeC + fi * 2048;
        }
    }
    const int par = l15 & 1;   // 0: even d (e-slot), 1: odd d (o-slot)

#pragma unroll
    for (int mt = 0; mt < 4; mt++) {
#pragma unroll
        for (int nt = 0; nt < 4; nt++) {
            const int n  = nbase + wc * 64 + nt * 16 + l15;
            const int mb = mbase + wr * 64 + mt * 16 + quad * 4;
            f32x4 v = acc[mt][nt];
            if (MODE == 0) {
                const int e = n & 1023;
                const int h = e >> 6, d = e & 63;
                if (proj_blk == 2) {
                    const int b_ = mb >> 11, s = mb & 2047;
                    const int bh = b_ * NHEAD + h;
                    uint2 pk;                           // fp16 V (RTZ)
                    pk.x = pk_f16(v[0], v[1]);
                    pk.y = pk_f16(v[2], v[3]);
                    *(uint2*)&oVt[((size_t)bh * DK + d) * S_LEN + s] = pk;
                } else {
                    u16* dst = (proj_blk == 0) ? oQ : oK;
                    // partner values (d^1 lives in lane^1)
                    float vp[4];
#pragma unroll
                    for (int r = 0; r < 4; r++) vp[r] = __shfl_xor(v[r], 1);
                    const int b_ = mb >> 11, s0 = mb & 2047;
                    const int bh = b_ * NHEAD + h;
                    const f32x4 sn = *(const f32x4*)(sB[nt] + s0);   // s0 % 4 == 0
                    const f32x4 cs = *(const f32x4*)(cB[nt] + s0);
#pragma unroll
                    for (int r = 0; r < 4; r++) {
                        const float res = par ? (vp[r] * sn[r] + v[r] * cs[r])
                                              : (v[r] * cs[r] - vp[r] * sn[r]);
                        dst[((size_t)bh * S_LEN + (s0 + r)) * DK + d] = f2bf(res);
                    }
                }
            } else {
#pragma unroll
                for (int r = 0; r < 4; r++)
                    oF[(size_t)(mb + r) * DM + n] = v[r];
            }
        }
    }
}

// ---------- causal flash attention: R12b — 8-wave 128-row blocks ----------
// R12 post-mortem: per-half 64-row blocks (R9) confirmed the latency/TLP theory
// (flash -17us via halved per-wave VGPR state + finer rebalancing) but DOUBLED
// K/V staging demand (~270->540 MB/iter), polluting L3 and costing gemm<0>
// +10us (FETCH 89->103MB). This version keeps BOTH wins: 128-row blocks (K/V
// staged ONCE per 128 q-rows, grid 1024) with 8 waves x 512 threads — waves
// 0-3 run half-0's four 16-row chains, waves 4-7 half-1's. Per-wave state =
// single chain (R9's VGPR win, same 16 waves/CU). Each wave stages 8 rows of
// K and V per tile (1+1 gl_lds16, ldsOff=wave*1024 — byte-identical LDS image
// to the 4-wave layout); counted wait vmcnt(2). Half-0 waves skip the fully-
// masked kt==2qt+1 compute (uniform per wave; barriers still hit). Per (row,kt)
// op order unchanged -> bitwise-identical output.
// T13 defer-max + SCL fold, T1 XCD remap, T5 setprio, raw-barrier dist-1 dbuf.
__global__ __launch_bounds__(512)
void flash_attn(const u16* __restrict__ Q, const u16* __restrict__ K,
                const u16* __restrict__ Vt, u16* __restrict__ Oc) {
    __shared__ u16 Ks[2][64 * 64];     // permuted k-rows, XOR chunk swizzle
    __shared__ u16 Vs[2][64 * 64];     // [d][s], XOR chunk swizzle
    const int lin = (int)blockIdx.x + 64 * (int)blockIdx.y;   // [0,1024)
    const int xcd = lin & 7, idx = lin >> 3;                  // idx in [0,128)
    const int bh  = xcd * 8 + (idx & 7);
    const int qt  = 15 - (idx >> 3);                          // [0,16), heavy first
    const int tid  = threadIdx.x;
    const int wave = tid >> 6, lane = tid & 63;
    const int hh   = wave >> 2, w4 = wave & 3;   // half, chain-within-half
    const int quad = lane >> 4, l15 = lane & 15;
    const int x7 = l15 & 7;
    const size_t headQK = (size_t)bh * S_LEN * DK;
    const size_t headVt = (size_t)bh * DK * S_LEN;
    const int b = bh >> 4, h = bh & 15;
    const float SCL = 0.18033688011112042f;   // (1/8) * log2(e)
    const float THRESH = 44.3614195558365f;   // 8 / SCL (defer-max, log2 bound 8)

    half8 ones;
#pragma unroll
    for (int j = 0; j < 8; j++) ones[j] = (_Float16)1.0f;

    // staging: 8 waves x 8 rows; rows rc = wave*8 + (lane>>3), chunk (lane&7)^rwl
    const int rwl  = lane >> 3;                 // row within 8-row slab
    const int scol = (lane & 7) ^ rwl;          // XOR-swizzled chunk column
    const int rc   = wave * 8 + rwl;
    const u16* gK = K  + headQK + (size_t)perm_inv(rc) * DK + scol * 8;
    const u16* gV = Vt + headVt + (size_t)rc * S_LEN + scol * 8;
    const int ldsOff = wave * 1024 + lane * 16;
    const int koff0 = (quad ^ x7) * 8;          // dk chunk 0..31, swizzled
    const int koff1 = ((4 + quad) ^ x7) * 8;    // dk chunk 32..63

    // Q B-fragments (one 16-row chain per wave)
    short8 qf0, qf1;
    {
        const int qrow = qt * 128 + hh * 64 + w4 * 16 + l15;
        qf0 = *(const short8*)&Q[headQK + (size_t)qrow * DK + quad * 8];
        qf1 = *(const short8*)&Q[headQK + (size_t)qrow * DK + 32 + quad * 8];
    }

    float m_st = -__builtin_inff();
    f32x4 lacc = (f32x4)0.0f;
    f32x4 oacc[4];
#pragma unroll
    for (int n = 0; n < 4; n++) oacc[n] = (f32x4)0.0f;

    const int NT = 2 * qt + 2;
    const int skip_kt = (hh == 0) ? (2 * qt + 1) : -1;   // fully masked for half 0
    const int diag_kt = 2 * qt + hh;
    // prologue: stage tile 0 into buffer 0 (2 loads per wave)
    gl_lds16(gK, (char*)Ks[0] + ldsOff);
    gl_lds16(gV, (char*)Vs[0] + ldsOff);

    for (int kt = 0; kt < NT; kt++) {
        const int cur = kt & 1, nxt = cur ^ 1;
        bar_raw();   // (A) everyone done reading buf[nxt]
        {            // prefetch tile kt+1 (clamped dummy on last iter)
            const int ktn = (kt + 1 < NT) ? kt + 1 : kt;
            gl_lds16(gK + (size_t)ktn * 64 * DK, (char*)Ks[nxt] + ldsOff);
            gl_lds16(gV + ktn * 64,              (char*)Vs[nxt] + ldsOff);
        }
        wait_vm2();  // tile kt's 2 loads retired; prefetch stays in flight
        bar_raw();   // (B) all waves' tile-kt staging visible

        if (kt == skip_kt) continue;   // wave-uniform; barriers already passed

        // ---- QK^T (scores RAW; SCL folded into exp2) ----
        f32x4 sc[4];
        __builtin_amdgcn_s_setprio(1);
#pragma unroll
        for (int nt = 0; nt < 4; nt++) {
            const int rb = (nt * 16 + l15) * 64;
            short8 kf0 = *(const short8*)&Ks[cur][rb + koff0];
            short8 kf1 = *(const short8*)&Ks[cur][rb + koff1];
            f32x4 z = (f32x4)0.0f;
            z = mfma_bf16(kf0, qf0, z);
            z = mfma_bf16(kf1, qf1, z);
            sc[nt] = z;
        }
        __builtin_amdgcn_s_setprio(0);

        if (kt == diag_kt) {   // diagonal tile: local k' > w4*16 + l15
            const int qloc = w4 * 16 + l15;
#pragma unroll
            for (int nt = 0; nt < 4; nt++) {
                const int kb = 32 * (nt >> 1) + 8 * quad + 4 * (nt & 1);
#pragma unroll
                for (int r = 0; r < 4; r++)
                    if (kb + r > qloc) sc[nt][r] = -__builtin_inff();
            }
        }
        // row max: in-lane over 16, then across quads
        float mx0 = fmaxf(fmaxf(sc[0][0], sc[0][1]), fmaxf(sc[0][2], sc[0][3]));
        float mx1 = fmaxf(fmaxf(sc[1][0], sc[1][1]), fmaxf(sc[1][2], sc[1][3]));
        float mx2 = fmaxf(fmaxf(sc[2][0], sc[2][1]), fmaxf(sc[2][2], sc[2][3]));
        float mx3 = fmaxf(fmaxf(sc[3][0], sc[3][1]), fmaxf(sc[3][2], sc[3][3]));
        float mx = fmaxf(fmaxf(mx0, mx1), fmaxf(mx2, mx3));
        mx = fmaxf(mx, __shfl_xor(mx, 16));
        mx = fmaxf(mx, __shfl_xor(mx, 32));
        // T13 defer-max: rescale only when some row's max grew past THRESH
        if (!__all(mx - m_st <= THRESH)) {
            const float mn = fmaxf(m_st, mx);
            const float alpha = __builtin_amdgcn_exp2f((m_st - mn) * SCL);
            m_st = mn;
            float alr[4];
#pragma unroll
            for (int r = 0; r < 4; r++) alr[r] = __shfl(alpha, quad * 20 + r);
#pragma unroll
            for (int n = 0; n < 4; n++)
#pragma unroll
                for (int r = 0; r < 4; r++) oacc[n][r] *= alr[r];
#pragma unroll
            for (int r = 0; r < 4; r++) lacc[r] *= alr[r];
        }
        // P = exp2(fma(sc, SCL, -m*SCL)); bounded by 2^8 when deferred
        const float msc = m_st * SCL;
#pragma unroll
        for (int nt = 0; nt < 4; nt++)
#pragma unroll
            for (int r = 0; r < 4; r++)
                sc[nt][r] = __builtin_amdgcn_exp2f(
                    __builtin_fmaf(sc[nt][r], SCL, -msc));
        u32 pw[8];
        pw[0] = pk_f16(sc[0][0], sc[0][1]); pw[1] = pk_f16(sc[0][2], sc[0][3]);
        pw[2] = pk_f16(sc[1][0], sc[1][1]); pw[3] = pk_f16(sc[1][2], sc[1][3]);
        pw[4] = pk_f16(sc[2][0], sc[2][1]); pw[5] = pk_f16(sc[2][2], sc[2][3]);
        pw[6] = pk_f16(sc[3][0], sc[3][1]); pw[7] = pk_f16(sc[3][2], sc[3][3]);
        half8 pf0 = __builtin_bit_cast(half8, *(uint4*)&pw[0]);
        half8 pf1 = __builtin_bit_cast(half8, *(uint4*)&pw[4]);

        // ---- PV + row-sum (fp16) ----
        __builtin_amdgcn_s_setprio(1);
#pragma unroll
        for (int c = 0; c < 2; c++) {
            const half8 pf = c ? pf1 : pf0;
            lacc = mfma_f16(pf, ones, lacc);
            const int voff = ((c * 4 + quad) ^ x7) * 8;
#pragma unroll
            for (int nt2 = 0; nt2 < 4; nt2++) {
                half8 vf = __builtin_bit_cast(half8,
                    *(const short8*)&Vs[cur][(nt2 * 16 + l15) * 64 + voff]);
                oacc[nt2] = mfma_f16(pf, vf, oacc[nt2]);
            }
        }
        __builtin_amdgcn_s_setprio(0);
    }
    wait_vm0();   // drain dangling dummy prefetch before exit

    // epilogue: rows quad*4+r, cols l15
#pragma unroll
    for (int r = 0; r < 4; r++) {
        const float inv = 1.0f / lacc[r];
        const int s = qt * 128 + hh * 64 + w4 * 16 + quad * 4 + r;
#pragma unroll
        for (int nt2 = 0; nt2 < 4; nt2++)
            Oc[((size_t)(b * S_LEN + s)) * DM + h * 64 + nt2 * 16 + l15] =
                f2bf(oacc[nt2][r] * inv);
    }
}

// ---------- workspace layout (u16 elements) ----------
#define OFF_XBF   ((size_t)0)
#define OFF_WCAT  ((size_t)8388608)
#define OFF_WO    ((size_t)11534336)
#define OFF_QB    ((size_t)12582912)
#define OFF_KB    ((size_t)20971520)
#define OFF_VT    ((size_t)29360128)
#define OFF_ROPE  ((size_t)37748736)   // 65536 fp32 sin + 65536 fp32 cos = 512 KB

extern "C" void kernel_launch(void* const* d_in, const int* in_sizes, int n_in,
                              void* d_out, int out_size, void* d_ws, size_t ws_size,
                              hipStream_t stream) {
    const float* x  = (const float*)d_in[0];
    const float* Wq = (const float*)d_in[1];
    const float* Wk = (const float*)d_in[2];
    const float* Wv = (const float*)d_in[3];
    const float* Wo = (const float*)d_in[4];
    u16* ws  = (u16*)d_ws;
    u16* XBF = ws + OFF_XBF;
    u16* WCA = ws + OFF_WCAT;
    u16* WOB = ws + OFF_WO;
    u16* QB  = ws + OFF_QB;
    u16* KB  = ws + OFF_KB;
    u16* VT  = ws + OFF_VT;
    float* ropeS = (float*)(ws + OFF_ROPE);
    float* ropeC = ropeS + 65536;
    u16* AT  = XBF;   // reuse

    cvt_all<<<12544, 256, 0, stream>>>((const float4*)x, (const float4*)Wq,
                                       (const float4*)Wk, (const float4*)Wv,
                                       (const float4*)Wo,
                                       (uint2*)XBF, (uint2*)WCA, (uint2*)WOB,
                                       ropeS, ropeC);

    gemm_nt<0><<<dim3(24, 64), 256, 0, stream>>>(XBF, WCA, QB, KB, VT, nullptr,
                                                 ropeS, ropeC);
    flash_attn<<<dim3(64, 16), 512, 0, stream>>>(QB, KB, VT, AT);
    gemm_nt<1><<<dim3(8, 64), 256, 0, stream>>>(AT, WOB, nullptr, nullptr, nullptr,
                                                (float*)d_out, nullptr, nullptr);
}